// Round 4
// baseline (849.612 us; speedup 1.0000x reference)
//
#include <hip/hip_runtime.h>
#include <math.h>

// Problem constants (fixed-shape problem)
#define DD 256
#define HH 4
#define CC 64
#define LL 5
#define NEG_SLOPE 0.2f
#define LH 20  // L*H

static __device__ __forceinline__ float lrelu(float x) {
    return x > 0.0f ? x : NEG_SLOPE * x;
}

// ---------------------------------------------------------------------------
// K0: wproj[k][l*4+h] = sum_c gat_ew[l][k][h*64+c] * att_edge[l][h][c]
__global__ __launch_bounds__(256) void wproj_kernel(
    const float* __restrict__ gat_ew, const float* __restrict__ att_edge,
    float* __restrict__ wproj) {
    int k = threadIdx.x;
    for (int l = 0; l < LL; ++l) {
        const float* W = gat_ew + (size_t)l * DD * DD;
        const float* att = att_edge + l * DD;  // [H][C] flat = 256
        for (int hh = 0; hh < HH; ++hh) {
            float s = 0.f;
            #pragma unroll
            for (int c = 0; c < CC; ++c)
                s += W[k * DD + hh * CC + c] * att[hh * CC + c];
            wproj[k * LH + l * HH + hh] = s;
        }
    }
}

// ---------------------------------------------------------------------------
// K1: node encoder h = relu(x @ enc_w + enc_b)
__global__ __launch_bounds__(256) void encoder_kernel(
    const float* __restrict__ x, const float* __restrict__ enc_w,
    const float* __restrict__ enc_b, float* __restrict__ h, int N) {
    int n = blockIdx.x;
    int tid = threadIdx.x;
    __shared__ float xs[42];
    if (tid < 42) xs[tid] = x[(size_t)n * 42 + tid];
    __syncthreads();
    float acc = enc_b[tid];
    #pragma unroll
    for (int f = 0; f < 42; ++f) acc += xs[f] * enc_w[f * DD + tid];
    h[(size_t)n * DD + tid] = fmaxf(acc, 0.f);
}

// ---------------------------------------------------------------------------
// K2: per-edge a_e[e][l*4+h] = relu(edge_attr[e]@eenc_w + eenc_b) . wproj[:,l*4+h]
// 2 edges per thread. All LDS reads wave-uniform (broadcast, conflict-free),
// vectorized as float4 (ds_read_b128): rows of 12 and 20 floats are 16B-aligned
// (48B / 80B strides). k-loop unrolled so LDS reads pipeline behind FMAs.
__global__ __launch_bounds__(256) void edge_pre_kernel(
    const float* __restrict__ edge_attr,
    const float* __restrict__ eenc_w, const float* __restrict__ eenc_b,
    const float* __restrict__ wproj, float* __restrict__ a_e_all, int E) {
    __shared__ float Wt[12 * 256];   // k-major: Wt[k*12+f]  (12 KB, 16B-aligned rows)
    __shared__ float wpl[256 * LH];  // wpl[k*20+j]          (20 KB, 16B-aligned rows)
    __shared__ float bs[256];        // eenc_b               (1 KB)
    int tid = threadIdx.x;
    for (int i = tid; i < 12 * 256; i += 256) {
        int k = i / 12, f = i % 12;
        Wt[i] = eenc_w[f * 256 + k];
    }
    for (int i = tid; i < 256 * LH; i += 256) wpl[i] = wproj[i];
    bs[tid] = eenc_b[tid];
    __syncthreads();

    int base = blockIdx.x * 512;
    int e0 = base + tid;
    int e1 = base + 256 + tid;
    bool v0 = e0 < E, v1 = e1 < E;
    float ea0[12], ea1[12];
    #pragma unroll
    for (int f = 0; f < 12; ++f) {
        ea0[f] = v0 ? edge_attr[(size_t)e0 * 12 + f] : 0.f;
        ea1[f] = v1 ? edge_attr[(size_t)e1 * 12 + f] : 0.f;
    }
    float acc0[LH] = {}, acc1[LH] = {};
    #pragma unroll 4
    for (int k = 0; k < 256; ++k) {
        const float4* wr4 = (const float4*)(Wt + k * 12);
        float w[12];
        *(float4*)&w[0] = wr4[0];
        *(float4*)&w[4] = wr4[1];
        *(float4*)&w[8] = wr4[2];
        float m0 = bs[k], m1 = m0;
        #pragma unroll
        for (int f = 0; f < 12; ++f) {
            m0 += ea0[f] * w[f];
            m1 += ea1[f] * w[f];
        }
        m0 = fmaxf(m0, 0.f);
        m1 = fmaxf(m1, 0.f);
        const float4* pr4 = (const float4*)(wpl + k * LH);
        float pw[LH];
        #pragma unroll
        for (int q = 0; q < 5; ++q) *(float4*)&pw[q * 4] = pr4[q];
        #pragma unroll
        for (int j = 0; j < LH; ++j) {
            acc0[j] += m0 * pw[j];
            acc1[j] += m1 * pw[j];
        }
    }
    if (v0) {
        #pragma unroll
        for (int j = 0; j < LH; ++j) a_e_all[(size_t)e0 * LH + j] = acc0[j];
    }
    if (v1) {
        #pragma unroll
        for (int j = 0; j < LH; ++j) a_e_all[(size_t)e1 * LH + j] = acc1[j];
    }
}

// ---------------------------------------------------------------------------
// deg histogram
__global__ void deg_kernel(const int* __restrict__ dst, int* __restrict__ deg, int E) {
    int e = blockIdx.x * 256 + threadIdx.x;
    if (e < E) atomicAdd(&deg[dst[e]], 1);
}

// K3: self-loop a_e = mean of incoming real-edge a_e (via CSR, no atomics)
__global__ void self_ae_kernel(const int* __restrict__ row_ptr,
                               const int* __restrict__ csr_eid,
                               float* __restrict__ a_e_all, int N, int E) {
    int i = blockIdx.x * 256 + threadIdx.x;
    if (i >= N * LH) return;
    int n = i / LH;
    int j = i % LH;
    int rs = row_ptr[n], re = row_ptr[n + 1];
    float s = 0.f;
    for (int k = rs; k < re; ++k)
        s += a_e_all[(size_t)csr_eid[k] * LH + j];
    a_e_all[(size_t)(E + n) * LH + j] = s / (float)max(re - rs, 1);
}

// ---------------------------------------------------------------------------
// K4: exclusive prefix scan of deg -> row_ptr  (single block)
__global__ __launch_bounds__(1024) void scan_kernel(const int* __restrict__ deg,
                                                    int* __restrict__ row_ptr, int n) {
    __shared__ int buf[1024];
    __shared__ int carry_s;
    int tid = threadIdx.x;
    if (tid == 0) carry_s = 0;
    __syncthreads();
    for (int base = 0; base < n; base += 1024) {
        int i = base + tid;
        int v = (i < n) ? deg[i] : 0;
        buf[tid] = v;
        __syncthreads();
        for (int off = 1; off < 1024; off <<= 1) {
            int t = (tid >= off) ? buf[tid - off] : 0;
            __syncthreads();
            buf[tid] += t;
            __syncthreads();
        }
        int carry = carry_s;
        if (i < n) row_ptr[i] = carry + buf[tid] - v;
        __syncthreads();
        if (tid == 1023) carry_s = carry + buf[1023];
        __syncthreads();
    }
    if (tid == 0) row_ptr[n] = carry_s;
}

__global__ void copy_int_kernel(const int* __restrict__ a, int* __restrict__ b, int n) {
    int i = blockIdx.x * 256 + threadIdx.x;
    if (i < n) b[i] = a[i];
}

// K4c: scatter edges into CSR order by dst
__global__ void scatter_kernel(const int* __restrict__ src, const int* __restrict__ dst,
                               int* __restrict__ cursor, int* __restrict__ csr_src,
                               int* __restrict__ csr_eid, int E) {
    int e = blockIdx.x * 256 + threadIdx.x;
    if (e >= E) return;
    int d = dst[e];
    int pos = atomicAdd(&cursor[d], 1);
    csr_src[pos] = src[e];
    csr_eid[pos] = e;
}

// ---------------------------------------------------------------------------
// GEMM: C[M,256] = A[M,256] @ W[256,256] (+bias, optional relu). fp32, 64x64 tile.
__global__ __launch_bounds__(256) void gemm256_kernel(
    const float* __restrict__ A, const float* __restrict__ W,
    const float* __restrict__ bias, float* __restrict__ C, int M, int do_relu) {
    __shared__ float As[16][68];
    __shared__ float Bs[16][68];
    int tid = threadIdx.x;
    int tx = tid & 15, ty = tid >> 4;
    int m0 = blockIdx.x * 64;
    int n0 = blockIdx.y * 64;
    float acc[4][4] = {};
    int arow = tid >> 2, aseg = tid & 3;
    int brow = tid >> 4, bseg = tid & 15;
    for (int k0 = 0; k0 < 256; k0 += 16) {
        float4 av = make_float4(0.f, 0.f, 0.f, 0.f);
        int grow = m0 + arow;
        if (grow < M) av = *(const float4*)(A + (size_t)grow * DD + k0 + aseg * 4);
        As[aseg * 4 + 0][arow] = av.x;
        As[aseg * 4 + 1][arow] = av.y;
        As[aseg * 4 + 2][arow] = av.z;
        As[aseg * 4 + 3][arow] = av.w;
        float4 bv = *(const float4*)(W + (size_t)(k0 + brow) * DD + n0 + bseg * 4);
        *(float4*)&Bs[brow][bseg * 4] = bv;
        __syncthreads();
        #pragma unroll
        for (int kk = 0; kk < 16; ++kk) {
            float a0 = As[kk][ty * 4 + 0], a1 = As[kk][ty * 4 + 1];
            float a2 = As[kk][ty * 4 + 2], a3 = As[kk][ty * 4 + 3];
            float b0 = Bs[kk][tx * 4 + 0], b1 = Bs[kk][tx * 4 + 1];
            float b2 = Bs[kk][tx * 4 + 2], b3 = Bs[kk][tx * 4 + 3];
            acc[0][0] += a0 * b0; acc[0][1] += a0 * b1; acc[0][2] += a0 * b2; acc[0][3] += a0 * b3;
            acc[1][0] += a1 * b0; acc[1][1] += a1 * b1; acc[1][2] += a1 * b2; acc[1][3] += a1 * b3;
            acc[2][0] += a2 * b0; acc[2][1] += a2 * b1; acc[2][2] += a2 * b2; acc[2][3] += a2 * b3;
            acc[3][0] += a3 * b0; acc[3][1] += a3 * b1; acc[3][2] += a3 * b2; acc[3][3] += a3 * b3;
        }
        __syncthreads();
    }
    #pragma unroll
    for (int i = 0; i < 4; ++i) {
        int r = m0 + ty * 4 + i;
        if (r >= M) continue;
        #pragma unroll
        for (int j = 0; j < 4; ++j) {
            int col = n0 + tx * 4 + j;
            float v = acc[i][j];
            if (bias) v += bias[col];
            if (do_relu) v = fmaxf(v, 0.f);
            C[(size_t)r * DD + col] = v;
        }
    }
}

// ---------------------------------------------------------------------------
// K5b: a_s[n,h], a_d[n,h] from xh
__global__ __launch_bounds__(256) void asd_kernel(
    const float* __restrict__ xh, const float* __restrict__ att_src,
    const float* __restrict__ att_dst, float* __restrict__ a_s, float* __restrict__ a_d) {
    int n = blockIdx.x;
    int tid = threadIdx.x;
    int hh = tid >> 6;
    float v = xh[(size_t)n * DD + tid];
    float ps = v * att_src[tid];  // att_src[l] is [H][C] flat == tid
    float pd = v * att_dst[tid];
    #pragma unroll
    for (int off = 32; off; off >>= 1) {
        ps += __shfl_xor(ps, off, 64);
        pd += __shfl_xor(pd, off, 64);
    }
    if ((tid & 63) == 0) {
        a_s[n * HH + hh] = ps;
        a_d[n * HH + hh] = pd;
    }
}

// ---------------------------------------------------------------------------
// K6: per-node softmax attention + aggregation + bias + LN + relu + residual
// a_e points at a_e_all + l*HH; per-edge value at a_e[e*LH + hh]
__global__ __launch_bounds__(256) void gat_message_kernel(
    const float* __restrict__ xh, const float* __restrict__ a_s,
    const float* __restrict__ a_d, const float* __restrict__ a_e,
    const int* __restrict__ row_ptr, const int* __restrict__ csr_src,
    const int* __restrict__ csr_eid, const float* __restrict__ gat_b,
    const float* __restrict__ ln_g, const float* __restrict__ ln_b,
    float* __restrict__ h, int N, int E) {
    int n = blockIdx.x;
    int tid = threadIdx.x;
    int hh = tid >> 6, c = tid & 63;
    int rs = row_ptr[n], re = row_ptr[n + 1];
    float adn = a_d[n * HH + hh];
    float al_self = lrelu(a_s[n * HH + hh] + adn + a_e[(size_t)(E + n) * LH + hh]);
    // pass 1: max
    float m = al_self;
    for (int k = rs + c; k < re; k += 64) {
        int s = csr_src[k], eid = csr_eid[k];
        m = fmaxf(m, lrelu(a_s[s * HH + hh] + adn + a_e[(size_t)eid * LH + hh]));
    }
    #pragma unroll
    for (int off = 32; off; off >>= 1) m = fmaxf(m, __shfl_xor(m, off, 64));
    // pass 2: denom
    float sden = 0.f;
    for (int k = rs + c; k < re; k += 64) {
        int s = csr_src[k], eid = csr_eid[k];
        sden += __expf(lrelu(a_s[s * HH + hh] + adn + a_e[(size_t)eid * LH + hh]) - m);
    }
    #pragma unroll
    for (int off = 32; off; off >>= 1) sden += __shfl_xor(sden, off, 64);
    sden += __expf(al_self - m);
    float inv_den = 1.0f / sden;
    // pass 3: weighted aggregation (all lanes walk all edges; xh row reads coalesced)
    float acc = __expf(al_self - m) * inv_den * xh[(size_t)n * DD + hh * CC + c];
    for (int k = rs; k < re; ++k) {
        int s = csr_src[k], eid = csr_eid[k];
        float w = __expf(lrelu(a_s[s * HH + hh] + adn + a_e[(size_t)eid * LH + hh]) - m) * inv_den;
        acc += w * xh[(size_t)s * DD + hh * CC + c];
    }
    float val = acc + gat_b[tid];
    // layernorm over 256
    __shared__ float s1[256], s2[256];
    s1[tid] = val;
    s2[tid] = val * val;
    __syncthreads();
    for (int off = 128; off; off >>= 1) {
        if (tid < off) { s1[tid] += s1[tid + off]; s2[tid] += s2[tid + off]; }
        __syncthreads();
    }
    float mu = s1[0] * (1.0f / DD);
    float var = s2[0] * (1.0f / DD) - mu * mu;
    float normed = (val - mu) * rsqrtf(var + 1e-5f) * ln_g[tid] + ln_b[tid];
    h[(size_t)n * DD + tid] += fmaxf(normed, 0.f);
}

// ---------------------------------------------------------------------------
// K7b: gate scalar per node
__global__ __launch_bounds__(256) void gate_kernel(
    const float* __restrict__ hid, const float* __restrict__ w2,
    const float* __restrict__ b2, float* __restrict__ gate, int N) {
    int n = blockIdx.x;
    int tid = threadIdx.x;
    __shared__ float red[256];
    red[tid] = hid[(size_t)n * DD + tid] * w2[tid];
    __syncthreads();
    for (int off = 128; off; off >>= 1) {
        if (tid < off) red[tid] += red[tid + off];
        __syncthreads();
    }
    if (tid == 0) gate[n] = red[0] + b2[0];
}

// K7pre: batch segment boundaries (batch is sorted)
__global__ void bstart_kernel(const int* __restrict__ batch, int* __restrict__ bstart,
                              int N, int B) {
    int b = threadIdx.x;
    if (b > B) return;
    int lo = 0, hi = N;
    while (lo < hi) {
        int mid = (lo + hi) >> 1;
        if (batch[mid] < b) lo = mid + 1; else hi = mid;
    }
    bstart[b] = lo;
}

// K7a: per-graph gate max + denom (B blocks)
__global__ __launch_bounds__(256) void gseg_kernel(
    const float* __restrict__ gate, const int* __restrict__ bstart,
    float* __restrict__ gmax, float* __restrict__ gden) {
    int b = blockIdx.x;
    int tid = threadIdx.x;
    int s0 = bstart[b], s1 = bstart[b + 1];
    __shared__ float red[256];
    float m = -1e30f;
    for (int i = s0 + tid; i < s1; i += 256) m = fmaxf(m, gate[i]);
    red[tid] = m;
    __syncthreads();
    for (int off = 128; off; off >>= 1) {
        if (tid < off) red[tid] = fmaxf(red[tid], red[tid + off]);
        __syncthreads();
    }
    float gm = red[0];
    __syncthreads();
    float s = 0.f;
    for (int i = s0 + tid; i < s1; i += 256) s += __expf(gate[i] - gm);
    red[tid] = s;
    __syncthreads();
    for (int off = 128; off; off >>= 1) {
        if (tid < off) red[tid] += red[tid + off];
        __syncthreads();
    }
    if (tid == 0) {
        gmax[b] = gm;
        gden[b] = red[0];
    }
}

// K7c: per-node pooling weight
__global__ void wgt_kernel(const float* __restrict__ gate, const int* __restrict__ batch,
                           const float* __restrict__ gmax, const float* __restrict__ gden,
                           float* __restrict__ wgt, int N) {
    int n = blockIdx.x * 256 + threadIdx.x;
    if (n >= N) return;
    int b = batch[n];
    wgt[n] = __expf(gate[n] - gmax[b]) / gden[b];
}

// K7d: scatter-accumulate pooled embedding. Each block: 32 consecutive nodes,
// register accumulate per dim (d = tid), flush on graph-boundary via atomicAdd.
#define POOL_CHUNK 32
__global__ __launch_bounds__(256) void pool_scatter_kernel(
    const float* __restrict__ h, const float* __restrict__ wgt,
    const int* __restrict__ batch, float* __restrict__ g_embed, int N) {
    int i0 = blockIdx.x * POOL_CHUNK;
    int d = threadIdx.x;
    int iend = min(i0 + POOL_CHUNK, N);
    float acc = 0.f;
    int cur = batch[i0];
    for (int i = i0; i < iend; ++i) {
        int b = batch[i];
        if (b != cur) {
            atomicAdd(&g_embed[cur * DD + d], acc);
            acc = 0.f;
            cur = b;
        }
        acc += wgt[i] * h[(size_t)i * DD + d];
    }
    atomicAdd(&g_embed[cur * DD + d], acc);
}

// K8: readout MLP [B,256] -> [B,256]
__global__ __launch_bounds__(256) void readout_kernel(
    const float* __restrict__ g_embed, const float* __restrict__ w1,
    const float* __restrict__ b1, const float* __restrict__ w2,
    const float* __restrict__ b2, float* __restrict__ out) {
    int b = blockIdx.x;
    int tid = threadIdx.x;
    __shared__ float gvec[256];
    __shared__ float hid[256];
    gvec[tid] = g_embed[b * DD + tid];
    __syncthreads();
    float hv = b1[tid];
    for (int k = 0; k < DD; ++k) hv += gvec[k] * w1[k * DD + tid];
    hid[tid] = fmaxf(hv, 0.f);
    __syncthreads();
    float o = b2[tid];
    for (int t = 0; t < DD; ++t) o += hid[t] * w2[t * DD + tid];
    out[b * DD + tid] = o;
}

// ---------------------------------------------------------------------------
extern "C" void kernel_launch(void* const* d_in, const int* in_sizes, int n_in,
                              void* d_out, int out_size, void* d_ws, size_t ws_size,
                              hipStream_t stream) {
    const float* x        = (const float*)d_in[0];
    const float* edge_attr= (const float*)d_in[1];
    const int*   edge_idx = (const int*)d_in[2];
    const int*   batch    = (const int*)d_in[3];
    const float* enc_w    = (const float*)d_in[4];
    const float* enc_b    = (const float*)d_in[5];
    const float* eenc_w   = (const float*)d_in[6];
    const float* eenc_b   = (const float*)d_in[7];
    const float* gat_w    = (const float*)d_in[8];
    const float* att_src  = (const float*)d_in[9];
    const float* att_dst  = (const float*)d_in[10];
    const float* att_edge = (const float*)d_in[11];
    const float* gat_ew   = (const float*)d_in[12];
    const float* gat_b    = (const float*)d_in[13];
    const float* ln_g     = (const float*)d_in[14];
    const float* ln_b     = (const float*)d_in[15];
    const float* gate_w1  = (const float*)d_in[16];
    const float* gate_b1  = (const float*)d_in[17];
    const float* gate_w2  = (const float*)d_in[18];
    const float* gate_b2  = (const float*)d_in[19];
    const float* ro_w1    = (const float*)d_in[20];
    const float* ro_b1    = (const float*)d_in[21];
    const float* ro_w2    = (const float*)d_in[22];
    const float* ro_b2    = (const float*)d_in[23];
    float* out = (float*)d_out;

    const int N = in_sizes[0] / 42;       // 10000
    const int E = in_sizes[1] / 12;       // 160000
    const int B = out_size / DD;          // 16

    // workspace carve-up
    char* p = (char*)d_ws;
    auto alloc = [&](size_t bytes) {
        char* r = p;
        p += (bytes + 255) & ~(size_t)255;
        return (void*)r;
    };
    float* h        = (float*)alloc((size_t)N * DD * 4);
    float* xh       = (float*)alloc((size_t)N * DD * 4);
    float* a_s      = (float*)alloc((size_t)N * HH * 4);
    float* a_d      = (float*)alloc((size_t)N * HH * 4);
    float* a_e_all  = (float*)alloc((size_t)(E + N) * LH * 4);  // [e][l*4+h]
    float* wproj    = (float*)alloc((size_t)DD * LH * 4);
    float* gate     = (float*)alloc((size_t)N * 4);
    float* g_embed  = (float*)alloc((size_t)B * DD * 4);
    float* gmax     = (float*)alloc((size_t)B * 4);
    float* gden     = (float*)alloc((size_t)B * 4);
    float* wgt      = (float*)alloc((size_t)N * 4);
    int* deg        = (int*)alloc((size_t)N * 4);
    int* row_ptr    = (int*)alloc((size_t)(N + 1) * 4);
    int* cursor     = (int*)alloc((size_t)N * 4);
    int* csr_src    = (int*)alloc((size_t)E * 4);
    int* csr_eid    = (int*)alloc((size_t)E * 4);
    int* bstart     = (int*)alloc((size_t)(B + 1) * 4);

    const int* src_arr = edge_idx;
    const int* dst_arr = edge_idx + E;

    hipMemsetAsync(deg, 0, (size_t)N * 4, stream);
    hipMemsetAsync(g_embed, 0, (size_t)B * DD * 4, stream);

    wproj_kernel<<<1, 256, 0, stream>>>(gat_ew, att_edge, wproj);
    encoder_kernel<<<N, 256, 0, stream>>>(x, enc_w, enc_b, h, N);
    deg_kernel<<<(E + 255) / 256, 256, 0, stream>>>(dst_arr, deg, E);
    scan_kernel<<<1, 1024, 0, stream>>>(deg, row_ptr, N);
    copy_int_kernel<<<(N + 255) / 256, 256, 0, stream>>>(row_ptr, cursor, N);
    scatter_kernel<<<(E + 255) / 256, 256, 0, stream>>>(
        src_arr, dst_arr, cursor, csr_src, csr_eid, E);
    edge_pre_kernel<<<(E + 511) / 512, 256, 0, stream>>>(
        edge_attr, eenc_w, eenc_b, wproj, a_e_all, E);
    self_ae_kernel<<<(N * LH + 255) / 256, 256, 0, stream>>>(
        row_ptr, csr_eid, a_e_all, N, E);

    dim3 ggrid((N + 63) / 64, 4);
    for (int l = 0; l < LL; ++l) {
        gemm256_kernel<<<ggrid, 256, 0, stream>>>(
            h, gat_w + (size_t)l * DD * DD, nullptr, xh, N, 0);
        asd_kernel<<<N, 256, 0, stream>>>(
            xh, att_src + l * DD, att_dst + l * DD, a_s, a_d);
        gat_message_kernel<<<N, 256, 0, stream>>>(
            xh, a_s, a_d, a_e_all + l * HH, row_ptr, csr_src, csr_eid,
            gat_b + l * DD, ln_g + l * DD, ln_b + l * DD, h, N, E);
    }

    // pooling gate MLP: hidden = relu(h @ gate_w1 + gate_b1) into xh (reuse)
    gemm256_kernel<<<ggrid, 256, 0, stream>>>(h, gate_w1, gate_b1, xh, N, 1);
    gate_kernel<<<N, 256, 0, stream>>>(xh, gate_w2, gate_b2, gate, N);
    bstart_kernel<<<1, 32, 0, stream>>>(batch, bstart, N, B);
    gseg_kernel<<<B, 256, 0, stream>>>(gate, bstart, gmax, gden);
    wgt_kernel<<<(N + 255) / 256, 256, 0, stream>>>(gate, batch, gmax, gden, wgt, N);
    pool_scatter_kernel<<<(N + POOL_CHUNK - 1) / POOL_CHUNK, 256, 0, stream>>>(
        h, wgt, batch, g_embed, N);
    readout_kernel<<<B, 256, 0, stream>>>(g_embed, ro_w1, ro_b1, ro_w2, ro_b2, out);
}

// Round 5
// 782.369 us; speedup vs baseline: 1.0859x; 1.0859x over previous
//
#include <hip/hip_runtime.h>
#include <math.h>

// Problem constants (fixed-shape problem)
#define DD 256
#define HH 4
#define CC 64
#define LL 5
#define NEG_SLOPE 0.2f
#define LH 20   // L*H
#define MAXD 768  // LDS softmax-weight cache cap (deg ~ Poisson(16), max ~45)

static __device__ __forceinline__ float lrelu(float x) {
    return x > 0.0f ? x : NEG_SLOPE * x;
}

// ---------------------------------------------------------------------------
// K0: wproj[k][l*4+h] = sum_c gat_ew[l][k][h*64+c] * att_edge[l][h][c]
__global__ __launch_bounds__(256) void wproj_kernel(
    const float* __restrict__ gat_ew, const float* __restrict__ att_edge,
    float* __restrict__ wproj) {
    int k = threadIdx.x;
    for (int l = 0; l < LL; ++l) {
        const float* W = gat_ew + (size_t)l * DD * DD;
        const float* att = att_edge + l * DD;  // [H][C] flat = 256
        for (int hh = 0; hh < HH; ++hh) {
            float s = 0.f;
            #pragma unroll
            for (int c = 0; c < CC; ++c)
                s += W[k * DD + hh * CC + c] * att[hh * CC + c];
            wproj[k * LH + l * HH + hh] = s;
        }
    }
}

// ---------------------------------------------------------------------------
// K1: node encoder h = relu(x @ enc_w + enc_b)
__global__ __launch_bounds__(256) void encoder_kernel(
    const float* __restrict__ x, const float* __restrict__ enc_w,
    const float* __restrict__ enc_b, float* __restrict__ h, int N) {
    int n = blockIdx.x;
    int tid = threadIdx.x;
    __shared__ float xs[42];
    if (tid < 42) xs[tid] = x[(size_t)n * 42 + tid];
    __syncthreads();
    float acc = enc_b[tid];
    #pragma unroll
    for (int f = 0; f < 42; ++f) acc += xs[f] * enc_w[f * DD + tid];
    h[(size_t)n * DD + tid] = fmaxf(acc, 0.f);
}

// ---------------------------------------------------------------------------
// K2: per-edge a_e[e][l*4+h] = relu(edge_attr[e]@eenc_w + eenc_b) . wproj[:,l*4+h]
// 2 edges/thread. LDS reads wave-uniform b128 broadcasts consumed directly as
// float4 temps (NO local-array staging, NO manual unroll — R3's regression).
__global__ __launch_bounds__(256) void edge_pre_kernel(
    const float* __restrict__ edge_attr,
    const float* __restrict__ eenc_w, const float* __restrict__ eenc_b,
    const float* __restrict__ wproj, float* __restrict__ a_e_all, int E) {
    __shared__ float Wt[12 * 256];   // k-major: Wt[k*12+f]  (48B rows, 16B aligned)
    __shared__ float wpl[256 * LH];  // wpl[k*20+j]          (80B rows, 16B aligned)
    __shared__ float bs[256];        // eenc_b
    int tid = threadIdx.x;
    for (int i = tid; i < 12 * 256; i += 256) {
        int k = i / 12, f = i % 12;
        Wt[i] = eenc_w[f * 256 + k];
    }
    for (int i = tid; i < 256 * LH; i += 256) wpl[i] = wproj[i];
    bs[tid] = eenc_b[tid];
    __syncthreads();

    int base = blockIdx.x * 512;
    int e0 = base + tid;
    int e1 = base + 256 + tid;
    bool v0 = e0 < E, v1 = e1 < E;
    float ea0[12] = {}, ea1[12] = {};
    if (v0) {
        const float4* p = (const float4*)(edge_attr + (size_t)e0 * 12);
        *(float4*)&ea0[0] = p[0]; *(float4*)&ea0[4] = p[1]; *(float4*)&ea0[8] = p[2];
    }
    if (v1) {
        const float4* p = (const float4*)(edge_attr + (size_t)e1 * 12);
        *(float4*)&ea1[0] = p[0]; *(float4*)&ea1[4] = p[1]; *(float4*)&ea1[8] = p[2];
    }
    float4 acc0[5], acc1[5];
    #pragma unroll
    for (int q = 0; q < 5; ++q) {
        acc0[q] = make_float4(0.f, 0.f, 0.f, 0.f);
        acc1[q] = make_float4(0.f, 0.f, 0.f, 0.f);
    }
    for (int k = 0; k < 256; ++k) {
        const float4* wr4 = (const float4*)(Wt + k * 12);
        float4 wa = wr4[0], wb = wr4[1], wc = wr4[2];
        float m0 = bs[k], m1 = m0;
        m0 += ea0[0] * wa.x + ea0[1] * wa.y + ea0[2] * wa.z + ea0[3] * wa.w
            + ea0[4] * wb.x + ea0[5] * wb.y + ea0[6] * wb.z + ea0[7] * wb.w
            + ea0[8] * wc.x + ea0[9] * wc.y + ea0[10] * wc.z + ea0[11] * wc.w;
        m1 += ea1[0] * wa.x + ea1[1] * wa.y + ea1[2] * wa.z + ea1[3] * wa.w
            + ea1[4] * wb.x + ea1[5] * wb.y + ea1[6] * wb.z + ea1[7] * wb.w
            + ea1[8] * wc.x + ea1[9] * wc.y + ea1[10] * wc.z + ea1[11] * wc.w;
        m0 = fmaxf(m0, 0.f);
        m1 = fmaxf(m1, 0.f);
        const float4* pr4 = (const float4*)(wpl + k * 20);
        #pragma unroll
        for (int q = 0; q < 5; ++q) {
            float4 p = pr4[q];
            acc0[q].x += m0 * p.x; acc0[q].y += m0 * p.y;
            acc0[q].z += m0 * p.z; acc0[q].w += m0 * p.w;
            acc1[q].x += m1 * p.x; acc1[q].y += m1 * p.y;
            acc1[q].z += m1 * p.z; acc1[q].w += m1 * p.w;
        }
    }
    if (v0) {
        float4* o = (float4*)(a_e_all + (size_t)e0 * LH);
        #pragma unroll
        for (int q = 0; q < 5; ++q) o[q] = acc0[q];
    }
    if (v1) {
        float4* o = (float4*)(a_e_all + (size_t)e1 * LH);
        #pragma unroll
        for (int q = 0; q < 5; ++q) o[q] = acc1[q];
    }
}

// ---------------------------------------------------------------------------
// deg histogram
__global__ void deg_kernel(const int* __restrict__ dst, int* __restrict__ deg, int E) {
    int e = blockIdx.x * 256 + threadIdx.x;
    if (e < E) atomicAdd(&deg[dst[e]], 1);
}

// K3: self-loop a_e = mean of incoming real-edge a_e (via CSR, no atomics)
__global__ void self_ae_kernel(const int* __restrict__ row_ptr,
                               const int* __restrict__ csr_eid,
                               float* __restrict__ a_e_all, int N, int E) {
    int i = blockIdx.x * 256 + threadIdx.x;
    if (i >= N * LH) return;
    int n = i / LH;
    int j = i % LH;
    int rs = row_ptr[n], re = row_ptr[n + 1];
    float s = 0.f;
    for (int k = rs; k < re; ++k)
        s += a_e_all[(size_t)csr_eid[k] * LH + j];
    a_e_all[(size_t)(E + n) * LH + j] = s / (float)max(re - rs, 1);
}

// ---------------------------------------------------------------------------
// K4: exclusive prefix scan of deg -> row_ptr  (single block)
__global__ __launch_bounds__(1024) void scan_kernel(const int* __restrict__ deg,
                                                    int* __restrict__ row_ptr, int n) {
    __shared__ int buf[1024];
    __shared__ int carry_s;
    int tid = threadIdx.x;
    if (tid == 0) carry_s = 0;
    __syncthreads();
    for (int base = 0; base < n; base += 1024) {
        int i = base + tid;
        int v = (i < n) ? deg[i] : 0;
        buf[tid] = v;
        __syncthreads();
        for (int off = 1; off < 1024; off <<= 1) {
            int t = (tid >= off) ? buf[tid - off] : 0;
            __syncthreads();
            buf[tid] += t;
            __syncthreads();
        }
        int carry = carry_s;
        if (i < n) row_ptr[i] = carry + buf[tid] - v;
        __syncthreads();
        if (tid == 1023) carry_s = carry + buf[1023];
        __syncthreads();
    }
    if (tid == 0) row_ptr[n] = carry_s;
}

__global__ void copy_int_kernel(const int* __restrict__ a, int* __restrict__ b, int n) {
    int i = blockIdx.x * 256 + threadIdx.x;
    if (i < n) b[i] = a[i];
}

// K4c: scatter edges into CSR order by dst
__global__ void scatter_kernel(const int* __restrict__ src, const int* __restrict__ dst,
                               int* __restrict__ cursor, int* __restrict__ csr_src,
                               int* __restrict__ csr_eid, int E) {
    int e = blockIdx.x * 256 + threadIdx.x;
    if (e >= E) return;
    int d = dst[e];
    int pos = atomicAdd(&cursor[d], 1);
    csr_src[pos] = src[e];
    csr_eid[pos] = e;
}

// ---------------------------------------------------------------------------
// GEMM: C[M,256] = A[M,256] @ W[256,256] (+bias, optional relu). fp32, 64x64 tile.
__global__ __launch_bounds__(256) void gemm256_kernel(
    const float* __restrict__ A, const float* __restrict__ W,
    const float* __restrict__ bias, float* __restrict__ C, int M, int do_relu) {
    __shared__ float As[16][68];
    __shared__ float Bs[16][68];
    int tid = threadIdx.x;
    int tx = tid & 15, ty = tid >> 4;
    int m0 = blockIdx.x * 64;
    int n0 = blockIdx.y * 64;
    float acc[4][4] = {};
    int arow = tid >> 2, aseg = tid & 3;
    int brow = tid >> 4, bseg = tid & 15;
    for (int k0 = 0; k0 < 256; k0 += 16) {
        float4 av = make_float4(0.f, 0.f, 0.f, 0.f);
        int grow = m0 + arow;
        if (grow < M) av = *(const float4*)(A + (size_t)grow * DD + k0 + aseg * 4);
        As[aseg * 4 + 0][arow] = av.x;
        As[aseg * 4 + 1][arow] = av.y;
        As[aseg * 4 + 2][arow] = av.z;
        As[aseg * 4 + 3][arow] = av.w;
        float4 bv = *(const float4*)(W + (size_t)(k0 + brow) * DD + n0 + bseg * 4);
        *(float4*)&Bs[brow][bseg * 4] = bv;
        __syncthreads();
        #pragma unroll
        for (int kk = 0; kk < 16; ++kk) {
            float a0 = As[kk][ty * 4 + 0], a1 = As[kk][ty * 4 + 1];
            float a2 = As[kk][ty * 4 + 2], a3 = As[kk][ty * 4 + 3];
            float b0 = Bs[kk][tx * 4 + 0], b1 = Bs[kk][tx * 4 + 1];
            float b2 = Bs[kk][tx * 4 + 2], b3 = Bs[kk][tx * 4 + 3];
            acc[0][0] += a0 * b0; acc[0][1] += a0 * b1; acc[0][2] += a0 * b2; acc[0][3] += a0 * b3;
            acc[1][0] += a1 * b0; acc[1][1] += a1 * b1; acc[1][2] += a1 * b2; acc[1][3] += a1 * b3;
            acc[2][0] += a2 * b0; acc[2][1] += a2 * b1; acc[2][2] += a2 * b2; acc[2][3] += a2 * b3;
            acc[3][0] += a3 * b0; acc[3][1] += a3 * b1; acc[3][2] += a3 * b2; acc[3][3] += a3 * b3;
        }
        __syncthreads();
    }
    #pragma unroll
    for (int i = 0; i < 4; ++i) {
        int r = m0 + ty * 4 + i;
        if (r >= M) continue;
        #pragma unroll
        for (int j = 0; j < 4; ++j) {
            int col = n0 + tx * 4 + j;
            float v = acc[i][j];
            if (bias) v += bias[col];
            if (do_relu) v = fmaxf(v, 0.f);
            C[(size_t)r * DD + col] = v;
        }
    }
}

// ---------------------------------------------------------------------------
// K5b: a_s[n,h], a_d[n,h] from xh
__global__ __launch_bounds__(256) void asd_kernel(
    const float* __restrict__ xh, const float* __restrict__ att_src,
    const float* __restrict__ att_dst, float* __restrict__ a_s, float* __restrict__ a_d) {
    int n = blockIdx.x;
    int tid = threadIdx.x;
    int hh = tid >> 6;
    float v = xh[(size_t)n * DD + tid];
    float ps = v * att_src[tid];  // att_src[l] is [H][C] flat == tid
    float pd = v * att_dst[tid];
    #pragma unroll
    for (int off = 32; off; off >>= 1) {
        ps += __shfl_xor(ps, off, 64);
        pd += __shfl_xor(pd, off, 64);
    }
    if ((tid & 63) == 0) {
        a_s[n * HH + hh] = ps;
        a_d[n * HH + hh] = pd;
    }
}

// ---------------------------------------------------------------------------
// K5c: per-edge pre-softmax logits alpha4[e] = lrelu(a_s4[src]+a_d4[dst]+ae4)
// a_e base passed as a_e_all + l*4 so the float4 at e*20 is this layer's slot.
__global__ void alpha_kernel(
    const float* __restrict__ a_s, const float* __restrict__ a_d,
    const float* __restrict__ a_e, const int* __restrict__ src,
    const int* __restrict__ dstp, float4* __restrict__ alpha4, int E, int N) {
    int e = blockIdx.x * 256 + threadIdx.x;
    if (e >= E + N) return;
    int s, d;
    if (e < E) { s = src[e]; d = dstp[e]; }
    else       { s = e - E; d = e - E; }
    float4 as = *(const float4*)(a_s + (size_t)s * 4);
    float4 ad = *(const float4*)(a_d + (size_t)d * 4);
    float4 ae = *(const float4*)(a_e + (size_t)e * 20);
    float4 r;
    r.x = lrelu(as.x + ad.x + ae.x);
    r.y = lrelu(as.y + ad.y + ae.y);
    r.z = lrelu(as.z + ad.z + ae.z);
    r.w = lrelu(as.w + ad.w + ae.w);
    alpha4[e] = r;
}

// ---------------------------------------------------------------------------
// K6: per-node softmax attention + aggregation + bias + LN + relu + residual.
// Merged online max+denom pass (one edge walk), raw alpha cached in LDS,
// converted in-place to softmax weights (wave-private rows, no barrier), then
// aggregation pass reads weights as free LDS broadcasts.
__global__ __launch_bounds__(256) void gat_message2_kernel(
    const float* __restrict__ xh, const float* __restrict__ alpha4f,
    const int* __restrict__ row_ptr, const int* __restrict__ csr_src,
    const int* __restrict__ csr_eid, const float* __restrict__ gat_b,
    const float* __restrict__ ln_g, const float* __restrict__ ln_b,
    float* __restrict__ h, int N, int E) {
    __shared__ float lw[4][MAXD];   // 12 KB
    __shared__ float s1[256], s2[256];
    int n = blockIdx.x;
    int tid = threadIdx.x;
    int hh = tid >> 6, c = tid & 63;
    int rs = row_ptr[n], re = row_ptr[n + 1];
    int deg = re - rs;
    float al_self = alpha4f[(size_t)(E + n) * 4 + hh];
    // merged online max + denom (lanes stride edges); cache raw alpha in LDS
    float m = al_self, den = 0.f;
    for (int k = rs + c; k < re; k += 64) {
        int kk = k - rs;
        float a = alpha4f[(size_t)csr_eid[k] * 4 + hh];
        if (kk < MAXD) lw[hh][kk] = a;
        float mn = fmaxf(m, a);
        den = den * __expf(m - mn) + __expf(a - mn);
        m = mn;
    }
    #pragma unroll
    for (int off = 32; off; off >>= 1) {
        float m2 = __shfl_xor(m, off, 64);
        float d2 = __shfl_xor(den, off, 64);
        float mn = fmaxf(m, m2);
        den = den * __expf(m - mn) + d2 * __expf(m2 - mn);
        m = mn;
    }
    den += __expf(al_self - m);
    float inv_den = 1.0f / den;
    // convert cached alpha -> softmax weight (wave-private LDS row, no barrier)
    int cap = min(deg, MAXD);
    for (int kk = c; kk < cap; kk += 64)
        lw[hh][kk] = __expf(lw[hh][kk] - m) * inv_den;
    // aggregation: all lanes walk edges; xh quarter-row reads coalesced per wave
    float acc = __expf(al_self - m) * inv_den * xh[(size_t)n * DD + tid];
    for (int k = rs; k < re; ++k) {
        int kk = k - rs;
        int s = csr_src[k];
        float w = (kk < MAXD) ? lw[hh][kk]
                              : __expf(alpha4f[(size_t)csr_eid[k] * 4 + hh] - m) * inv_den;
        acc += w * xh[(size_t)s * DD + tid];
    }
    float val = acc + gat_b[tid];
    // layernorm over 256
    s1[tid] = val;
    s2[tid] = val * val;
    __syncthreads();
    for (int off = 128; off; off >>= 1) {
        if (tid < off) { s1[tid] += s1[tid + off]; s2[tid] += s2[tid + off]; }
        __syncthreads();
    }
    float mu = s1[0] * (1.0f / DD);
    float var = s2[0] * (1.0f / DD) - mu * mu;
    float normed = (val - mu) * rsqrtf(var + 1e-5f) * ln_g[tid] + ln_b[tid];
    h[(size_t)n * DD + tid] += fmaxf(normed, 0.f);
}

// ---------------------------------------------------------------------------
// K7b: gate scalar per node
__global__ __launch_bounds__(256) void gate_kernel(
    const float* __restrict__ hid, const float* __restrict__ w2,
    const float* __restrict__ b2, float* __restrict__ gate, int N) {
    int n = blockIdx.x;
    int tid = threadIdx.x;
    __shared__ float red[256];
    red[tid] = hid[(size_t)n * DD + tid] * w2[tid];
    __syncthreads();
    for (int off = 128; off; off >>= 1) {
        if (tid < off) red[tid] += red[tid + off];
        __syncthreads();
    }
    if (tid == 0) gate[n] = red[0] + b2[0];
}

// K7pre: batch segment boundaries (batch is sorted)
__global__ void bstart_kernel(const int* __restrict__ batch, int* __restrict__ bstart,
                              int N, int B) {
    int b = threadIdx.x;
    if (b > B) return;
    int lo = 0, hi = N;
    while (lo < hi) {
        int mid = (lo + hi) >> 1;
        if (batch[mid] < b) lo = mid + 1; else hi = mid;
    }
    bstart[b] = lo;
}

// K7a: per-graph gate max + denom (B blocks)
__global__ __launch_bounds__(256) void gseg_kernel(
    const float* __restrict__ gate, const int* __restrict__ bstart,
    float* __restrict__ gmax, float* __restrict__ gden) {
    int b = blockIdx.x;
    int tid = threadIdx.x;
    int s0 = bstart[b], s1 = bstart[b + 1];
    __shared__ float red[256];
    float m = -1e30f;
    for (int i = s0 + tid; i < s1; i += 256) m = fmaxf(m, gate[i]);
    red[tid] = m;
    __syncthreads();
    for (int off = 128; off; off >>= 1) {
        if (tid < off) red[tid] = fmaxf(red[tid], red[tid + off]);
        __syncthreads();
    }
    float gm = red[0];
    __syncthreads();
    float s = 0.f;
    for (int i = s0 + tid; i < s1; i += 256) s += __expf(gate[i] - gm);
    red[tid] = s;
    __syncthreads();
    for (int off = 128; off; off >>= 1) {
        if (tid < off) red[tid] += red[tid + off];
        __syncthreads();
    }
    if (tid == 0) {
        gmax[b] = gm;
        gden[b] = red[0];
    }
}

// K7c: per-node pooling weight
__global__ void wgt_kernel(const float* __restrict__ gate, const int* __restrict__ batch,
                           const float* __restrict__ gmax, const float* __restrict__ gden,
                           float* __restrict__ wgt, int N) {
    int n = blockIdx.x * 256 + threadIdx.x;
    if (n >= N) return;
    int b = batch[n];
    wgt[n] = __expf(gate[n] - gmax[b]) / gden[b];
}

// K7d: scatter-accumulate pooled embedding.
#define POOL_CHUNK 32
__global__ __launch_bounds__(256) void pool_scatter_kernel(
    const float* __restrict__ h, const float* __restrict__ wgt,
    const int* __restrict__ batch, float* __restrict__ g_embed, int N) {
    int i0 = blockIdx.x * POOL_CHUNK;
    int d = threadIdx.x;
    int iend = min(i0 + POOL_CHUNK, N);
    float acc = 0.f;
    int cur = batch[i0];
    for (int i = i0; i < iend; ++i) {
        int b = batch[i];
        if (b != cur) {
            atomicAdd(&g_embed[cur * DD + d], acc);
            acc = 0.f;
            cur = b;
        }
        acc += wgt[i] * h[(size_t)i * DD + d];
    }
    atomicAdd(&g_embed[cur * DD + d], acc);
}

// K8: readout MLP [B,256] -> [B,256]
__global__ __launch_bounds__(256) void readout_kernel(
    const float* __restrict__ g_embed, const float* __restrict__ w1,
    const float* __restrict__ b1, const float* __restrict__ w2,
    const float* __restrict__ b2, float* __restrict__ out) {
    int b = blockIdx.x;
    int tid = threadIdx.x;
    __shared__ float gvec[256];
    __shared__ float hid[256];
    gvec[tid] = g_embed[b * DD + tid];
    __syncthreads();
    float hv = b1[tid];
    for (int k = 0; k < DD; ++k) hv += gvec[k] * w1[k * DD + tid];
    hid[tid] = fmaxf(hv, 0.f);
    __syncthreads();
    float o = b2[tid];
    for (int t = 0; t < DD; ++t) o += hid[t] * w2[t * DD + tid];
    out[b * DD + tid] = o;
}

// ---------------------------------------------------------------------------
extern "C" void kernel_launch(void* const* d_in, const int* in_sizes, int n_in,
                              void* d_out, int out_size, void* d_ws, size_t ws_size,
                              hipStream_t stream) {
    const float* x        = (const float*)d_in[0];
    const float* edge_attr= (const float*)d_in[1];
    const int*   edge_idx = (const int*)d_in[2];
    const int*   batch    = (const int*)d_in[3];
    const float* enc_w    = (const float*)d_in[4];
    const float* enc_b    = (const float*)d_in[5];
    const float* eenc_w   = (const float*)d_in[6];
    const float* eenc_b   = (const float*)d_in[7];
    const float* gat_w    = (const float*)d_in[8];
    const float* att_src  = (const float*)d_in[9];
    const float* att_dst  = (const float*)d_in[10];
    const float* att_edge = (const float*)d_in[11];
    const float* gat_ew   = (const float*)d_in[12];
    const float* gat_b    = (const float*)d_in[13];
    const float* ln_g     = (const float*)d_in[14];
    const float* ln_b     = (const float*)d_in[15];
    const float* gate_w1  = (const float*)d_in[16];
    const float* gate_b1  = (const float*)d_in[17];
    const float* gate_w2  = (const float*)d_in[18];
    const float* gate_b2  = (const float*)d_in[19];
    const float* ro_w1    = (const float*)d_in[20];
    const float* ro_b1    = (const float*)d_in[21];
    const float* ro_w2    = (const float*)d_in[22];
    const float* ro_b2    = (const float*)d_in[23];
    float* out = (float*)d_out;

    const int N = in_sizes[0] / 42;       // 10000
    const int E = in_sizes[1] / 12;       // 160000
    const int B = out_size / DD;          // 16

    // workspace carve-up
    char* p = (char*)d_ws;
    auto alloc = [&](size_t bytes) {
        char* r = p;
        p += (bytes + 255) & ~(size_t)255;
        return (void*)r;
    };
    float* h        = (float*)alloc((size_t)N * DD * 4);
    float* xh       = (float*)alloc((size_t)N * DD * 4);
    float* a_s      = (float*)alloc((size_t)N * HH * 4);
    float* a_d      = (float*)alloc((size_t)N * HH * 4);
    float* a_e_all  = (float*)alloc((size_t)(E + N) * LH * 4);  // [e][l*4+h]
    float* alpha4   = (float*)alloc((size_t)(E + N) * 4 * 4);   // [e][4], per-layer reuse
    float* wproj    = (float*)alloc((size_t)DD * LH * 4);
    float* gate     = (float*)alloc((size_t)N * 4);
    float* g_embed  = (float*)alloc((size_t)B * DD * 4);
    float* gmax     = (float*)alloc((size_t)B * 4);
    float* gden     = (float*)alloc((size_t)B * 4);
    float* wgt      = (float*)alloc((size_t)N * 4);
    int* deg        = (int*)alloc((size_t)N * 4);
    int* row_ptr    = (int*)alloc((size_t)(N + 1) * 4);
    int* cursor     = (int*)alloc((size_t)N * 4);
    int* csr_src    = (int*)alloc((size_t)E * 4);
    int* csr_eid    = (int*)alloc((size_t)E * 4);
    int* bstart     = (int*)alloc((size_t)(B + 1) * 4);

    const int* src_arr = edge_idx;
    const int* dst_arr = edge_idx + E;

    hipMemsetAsync(deg, 0, (size_t)N * 4, stream);
    hipMemsetAsync(g_embed, 0, (size_t)B * DD * 4, stream);

    wproj_kernel<<<1, 256, 0, stream>>>(gat_ew, att_edge, wproj);
    encoder_kernel<<<N, 256, 0, stream>>>(x, enc_w, enc_b, h, N);
    deg_kernel<<<(E + 255) / 256, 256, 0, stream>>>(dst_arr, deg, E);
    scan_kernel<<<1, 1024, 0, stream>>>(deg, row_ptr, N);
    copy_int_kernel<<<(N + 255) / 256, 256, 0, stream>>>(row_ptr, cursor, N);
    scatter_kernel<<<(E + 255) / 256, 256, 0, stream>>>(
        src_arr, dst_arr, cursor, csr_src, csr_eid, E);
    edge_pre_kernel<<<(E + 511) / 512, 256, 0, stream>>>(
        edge_attr, eenc_w, eenc_b, wproj, a_e_all, E);
    self_ae_kernel<<<(N * LH + 255) / 256, 256, 0, stream>>>(
        row_ptr, csr_eid, a_e_all, N, E);

    dim3 ggrid((N + 63) / 64, 4);
    for (int l = 0; l < LL; ++l) {
        gemm256_kernel<<<ggrid, 256, 0, stream>>>(
            h, gat_w + (size_t)l * DD * DD, nullptr, xh, N, 0);
        asd_kernel<<<N, 256, 0, stream>>>(
            xh, att_src + l * DD, att_dst + l * DD, a_s, a_d);
        alpha_kernel<<<(E + N + 255) / 256, 256, 0, stream>>>(
            a_s, a_d, a_e_all + l * HH, src_arr, dst_arr, (float4*)alpha4, E, N);
        gat_message2_kernel<<<N, 256, 0, stream>>>(
            xh, alpha4, row_ptr, csr_src, csr_eid,
            gat_b + l * DD, ln_g + l * DD, ln_b + l * DD, h, N, E);
    }

    // pooling gate MLP: hidden = relu(h @ gate_w1 + gate_b1) into xh (reuse)
    gemm256_kernel<<<ggrid, 256, 0, stream>>>(h, gate_w1, gate_b1, xh, N, 1);
    gate_kernel<<<N, 256, 0, stream>>>(xh, gate_w2, gate_b2, gate, N);
    bstart_kernel<<<1, 32, 0, stream>>>(batch, bstart, N, B);
    gseg_kernel<<<B, 256, 0, stream>>>(gate, bstart, gmax, gden);
    wgt_kernel<<<(N + 255) / 256, 256, 0, stream>>>(gate, batch, gmax, gden, wgt, N);
    pool_scatter_kernel<<<(N + POOL_CHUNK - 1) / POOL_CHUNK, 256, 0, stream>>>(
        h, wgt, batch, g_embed, N);
    readout_kernel<<<B, 256, 0, stream>>>(g_embed, ro_w1, ro_b1, ro_w2, ro_b2, out);
}

// Round 6
// 707.969 us; speedup vs baseline: 1.2001x; 1.1051x over previous
//
#include <hip/hip_runtime.h>
#include <math.h>

// Problem constants (fixed-shape problem)
#define DD 256
#define HH 4
#define CC 64
#define LL 5
#define NEG_SLOPE 0.2f
#define LH 20   // L*H
#define MAXD 768  // LDS softmax-weight cache cap

static __device__ __forceinline__ float lrelu(float x) {
    return x > 0.0f ? x : NEG_SLOPE * x;
}

// ---------------------------------------------------------------------------
// K0: wproj[k][l*4+h] = sum_c gat_ew[l][k][h*64+c] * att_edge[l][h][c]
__global__ __launch_bounds__(256) void wproj_kernel(
    const float* __restrict__ gat_ew, const float* __restrict__ att_edge,
    float* __restrict__ wproj) {
    int l = blockIdx.x;
    int k = threadIdx.x;
    const float* W = gat_ew + (size_t)l * DD * DD;
    const float* att = att_edge + l * DD;  // [H][C] flat = 256
    for (int hh = 0; hh < HH; ++hh) {
        float s = 0.f;
        #pragma unroll
        for (int c = 0; c < CC; ++c)
            s += W[k * DD + hh * CC + c] * att[hh * CC + c];
        wproj[k * LH + l * HH + hh] = s;
    }
}

// ---------------------------------------------------------------------------
// K1: node encoder h = relu(x @ enc_w + enc_b)
__global__ __launch_bounds__(256) void encoder_kernel(
    const float* __restrict__ x, const float* __restrict__ enc_w,
    const float* __restrict__ enc_b, float* __restrict__ h, int N) {
    int n = blockIdx.x;
    int tid = threadIdx.x;
    __shared__ float xs[42];
    if (tid < 42) xs[tid] = x[(size_t)n * 42 + tid];
    __syncthreads();
    float acc = enc_b[tid];
    #pragma unroll
    for (int f = 0; f < 42; ++f) acc += xs[f] * enc_w[f * DD + tid];
    h[(size_t)n * DD + tid] = fmaxf(acc, 0.f);
}

// ---------------------------------------------------------------------------
// K2: per-edge a_e[e][l*4+h] = relu(edge_attr[e]@eenc_w + eenc_b) . wproj[:,l*4+h]
// 1 edge/thread (625 blocks -> ~10 waves/CU for latency hiding). All LDS reads
// are wave-uniform b128 broadcasts consumed directly as float4 temps.
__global__ __launch_bounds__(256) void edge_pre_kernel(
    const float* __restrict__ edge_attr,
    const float* __restrict__ eenc_w, const float* __restrict__ eenc_b,
    const float* __restrict__ wproj, float* __restrict__ a_e_all, int E) {
    __shared__ float Wt[12 * 256];   // k-major: Wt[k*12+f]  (48B rows, 16B aligned)
    __shared__ float wpl[256 * LH];  // wpl[k*20+j]          (80B rows, 16B aligned)
    __shared__ float bs[256];        // eenc_b
    int tid = threadIdx.x;
    for (int i = tid; i < 12 * 256; i += 256) {
        int k = i / 12, f = i % 12;
        Wt[i] = eenc_w[f * 256 + k];
    }
    for (int i = tid; i < 256 * LH; i += 256) wpl[i] = wproj[i];
    bs[tid] = eenc_b[tid];
    __syncthreads();

    int e = blockIdx.x * 256 + tid;
    bool v = e < E;
    float ea[12] = {};
    if (v) {
        const float4* p = (const float4*)(edge_attr + (size_t)e * 12);
        *(float4*)&ea[0] = p[0]; *(float4*)&ea[4] = p[1]; *(float4*)&ea[8] = p[2];
    }
    float4 acc[5];
    #pragma unroll
    for (int q = 0; q < 5; ++q) acc[q] = make_float4(0.f, 0.f, 0.f, 0.f);
    for (int k = 0; k < 256; ++k) {
        const float4* wr4 = (const float4*)(Wt + k * 12);
        float4 wa = wr4[0], wb = wr4[1], wc = wr4[2];
        float m0 = bs[k];
        m0 += ea[0] * wa.x + ea[1] * wa.y + ea[2] * wa.z + ea[3] * wa.w
            + ea[4] * wb.x + ea[5] * wb.y + ea[6] * wb.z + ea[7] * wb.w
            + ea[8] * wc.x + ea[9] * wc.y + ea[10] * wc.z + ea[11] * wc.w;
        m0 = fmaxf(m0, 0.f);
        const float4* pr4 = (const float4*)(wpl + k * 20);
        #pragma unroll
        for (int q = 0; q < 5; ++q) {
            float4 p = pr4[q];
            acc[q].x += m0 * p.x; acc[q].y += m0 * p.y;
            acc[q].z += m0 * p.z; acc[q].w += m0 * p.w;
        }
    }
    if (v) {
        float4* o = (float4*)(a_e_all + (size_t)e * LH);
        #pragma unroll
        for (int q = 0; q < 5; ++q) o[q] = acc[q];
    }
}

// ---------------------------------------------------------------------------
// deg histogram
__global__ void deg_kernel(const int* __restrict__ dst, int* __restrict__ deg, int E) {
    int e = blockIdx.x * 256 + threadIdx.x;
    if (e < E) atomicAdd(&deg[dst[e]], 1);
}

// K3: self-loop a_e = mean of incoming real-edge a_e (via CSR, no atomics)
__global__ void self_ae_kernel(const int* __restrict__ row_ptr,
                               const int* __restrict__ csr_eid,
                               float* __restrict__ a_e_all, int N, int E) {
    int i = blockIdx.x * 256 + threadIdx.x;
    if (i >= N * LH) return;
    int n = i / LH;
    int j = i % LH;
    int rs = row_ptr[n], re = row_ptr[n + 1];
    float s = 0.f;
    for (int k = rs; k < re; ++k)
        s += a_e_all[(size_t)csr_eid[k] * LH + j];
    a_e_all[(size_t)(E + n) * LH + j] = s / (float)max(re - rs, 1);
}

// ---------------------------------------------------------------------------
// K4: exclusive prefix scan of deg -> row_ptr  (single block)
__global__ __launch_bounds__(1024) void scan_kernel(const int* __restrict__ deg,
                                                    int* __restrict__ row_ptr, int n) {
    __shared__ int buf[1024];
    __shared__ int carry_s;
    int tid = threadIdx.x;
    if (tid == 0) carry_s = 0;
    __syncthreads();
    for (int base = 0; base < n; base += 1024) {
        int i = base + tid;
        int v = (i < n) ? deg[i] : 0;
        buf[tid] = v;
        __syncthreads();
        for (int off = 1; off < 1024; off <<= 1) {
            int t = (tid >= off) ? buf[tid - off] : 0;
            __syncthreads();
            buf[tid] += t;
            __syncthreads();
        }
        int carry = carry_s;
        if (i < n) row_ptr[i] = carry + buf[tid] - v;
        __syncthreads();
        if (tid == 1023) carry_s = carry + buf[1023];
        __syncthreads();
    }
    if (tid == 0) row_ptr[n] = carry_s;
}

__global__ void copy_int_kernel(const int* __restrict__ a, int* __restrict__ b, int n) {
    int i = blockIdx.x * 256 + threadIdx.x;
    if (i < n) b[i] = a[i];
}

// K4c: scatter edges into CSR order by dst
__global__ void scatter_kernel(const int* __restrict__ src, const int* __restrict__ dst,
                               int* __restrict__ cursor, int* __restrict__ csr_src,
                               int* __restrict__ csr_eid, int E) {
    int e = blockIdx.x * 256 + threadIdx.x;
    if (e >= E) return;
    int d = dst[e];
    int pos = atomicAdd(&cursor[d], 1);
    csr_src[pos] = src[e];
    csr_eid[pos] = e;
}

// ---------------------------------------------------------------------------
// GEMM: C[M,256] = A[M,256] @ W[256,256] (+bias, optional relu). fp32, 64x64 tile.
// Fused epilogue (att_src != nullptr): since the 64-col tile == one head,
// computes a_s[row][head], a_d[row][head] from acc via LDS reduction.
__global__ __launch_bounds__(256) void gemm256_kernel(
    const float* __restrict__ A, const float* __restrict__ W,
    const float* __restrict__ bias, float* __restrict__ C, int M, int do_relu,
    const float* __restrict__ att_src, const float* __restrict__ att_dst,
    float* __restrict__ a_s, float* __restrict__ a_d) {
    __shared__ float As[16][68];
    __shared__ float Bs[16][68];
    __shared__ float reds[64][17];
    __shared__ float redd[64][17];
    int tid = threadIdx.x;
    int tx = tid & 15, ty = tid >> 4;
    int m0 = blockIdx.x * 64;
    int n0 = blockIdx.y * 64;
    float acc[4][4] = {};
    int arow = tid >> 2, aseg = tid & 3;
    int brow = tid >> 4, bseg = tid & 15;
    for (int k0 = 0; k0 < 256; k0 += 16) {
        float4 av = make_float4(0.f, 0.f, 0.f, 0.f);
        int grow = m0 + arow;
        if (grow < M) av = *(const float4*)(A + (size_t)grow * DD + k0 + aseg * 4);
        As[aseg * 4 + 0][arow] = av.x;
        As[aseg * 4 + 1][arow] = av.y;
        As[aseg * 4 + 2][arow] = av.z;
        As[aseg * 4 + 3][arow] = av.w;
        float4 bv = *(const float4*)(W + (size_t)(k0 + brow) * DD + n0 + bseg * 4);
        *(float4*)&Bs[brow][bseg * 4] = bv;
        __syncthreads();
        #pragma unroll
        for (int kk = 0; kk < 16; ++kk) {
            float a0 = As[kk][ty * 4 + 0], a1 = As[kk][ty * 4 + 1];
            float a2 = As[kk][ty * 4 + 2], a3 = As[kk][ty * 4 + 3];
            float b0 = Bs[kk][tx * 4 + 0], b1 = Bs[kk][tx * 4 + 1];
            float b2 = Bs[kk][tx * 4 + 2], b3 = Bs[kk][tx * 4 + 3];
            acc[0][0] += a0 * b0; acc[0][1] += a0 * b1; acc[0][2] += a0 * b2; acc[0][3] += a0 * b3;
            acc[1][0] += a1 * b0; acc[1][1] += a1 * b1; acc[1][2] += a1 * b2; acc[1][3] += a1 * b3;
            acc[2][0] += a2 * b0; acc[2][1] += a2 * b1; acc[2][2] += a2 * b2; acc[2][3] += a2 * b3;
            acc[3][0] += a3 * b0; acc[3][1] += a3 * b1; acc[3][2] += a3 * b2; acc[3][3] += a3 * b3;
        }
        __syncthreads();
    }
    #pragma unroll
    for (int i = 0; i < 4; ++i) {
        int r = m0 + ty * 4 + i;
        if (r >= M) continue;
        #pragma unroll
        for (int j = 0; j < 4; ++j) {
            int col = n0 + tx * 4 + j;
            float v = acc[i][j];
            if (bias) v += bias[col];
            if (do_relu) v = fmaxf(v, 0.f);
            C[(size_t)r * DD + col] = v;
        }
    }
    if (att_src) {
        float ps[4] = {}, pd[4] = {};
        #pragma unroll
        for (int j = 0; j < 4; ++j) {
            float ws = att_src[n0 + tx * 4 + j];
            float wd = att_dst[n0 + tx * 4 + j];
            #pragma unroll
            for (int i = 0; i < 4; ++i) {
                ps[i] += acc[i][j] * ws;
                pd[i] += acc[i][j] * wd;
            }
        }
        #pragma unroll
        for (int i = 0; i < 4; ++i) {
            reds[ty * 4 + i][tx] = ps[i];
            redd[ty * 4 + i][tx] = pd[i];
        }
        __syncthreads();
        if (tid < 64) {
            float ss = 0.f, sd = 0.f;
            #pragma unroll
            for (int t = 0; t < 16; ++t) { ss += reds[tid][t]; sd += redd[tid][t]; }
            int r = m0 + tid;
            if (r < M) {
                a_s[r * HH + blockIdx.y] = ss;
                a_d[r * HH + blockIdx.y] = sd;
            }
        }
    }
}

// ---------------------------------------------------------------------------
// K5c: per-edge pre-softmax logits alpha4[e] = lrelu(a_s4[src]+a_d4[dst]+ae4)
__global__ void alpha_kernel(
    const float* __restrict__ a_s, const float* __restrict__ a_d,
    const float* __restrict__ a_e, const int* __restrict__ src,
    const int* __restrict__ dstp, float4* __restrict__ alpha4, int E, int N) {
    int e = blockIdx.x * 256 + threadIdx.x;
    if (e >= E + N) return;
    int s, d;
    if (e < E) { s = src[e]; d = dstp[e]; }
    else       { s = e - E; d = e - E; }
    float4 as = *(const float4*)(a_s + (size_t)s * 4);
    float4 ad = *(const float4*)(a_d + (size_t)d * 4);
    float4 ae = *(const float4*)(a_e + (size_t)e * 20);
    float4 r;
    r.x = lrelu(as.x + ad.x + ae.x);
    r.y = lrelu(as.y + ad.y + ae.y);
    r.z = lrelu(as.z + ad.z + ae.z);
    r.w = lrelu(as.w + ad.w + ae.w);
    alpha4[e] = r;
}

// ---------------------------------------------------------------------------
// K6: per-node softmax attention + aggregation + bias + LN + relu + residual.
__global__ __launch_bounds__(256) void gat_message2_kernel(
    const float* __restrict__ xh, const float* __restrict__ alpha4f,
    const int* __restrict__ row_ptr, const int* __restrict__ csr_src,
    const int* __restrict__ csr_eid, const float* __restrict__ gat_b,
    const float* __restrict__ ln_g, const float* __restrict__ ln_b,
    float* __restrict__ h, int N, int E) {
    __shared__ float lw[4][MAXD];   // 12 KB
    __shared__ float s1[256], s2[256];
    int n = blockIdx.x;
    int tid = threadIdx.x;
    int hh = tid >> 6, c = tid & 63;
    int rs = row_ptr[n], re = row_ptr[n + 1];
    int deg = re - rs;
    float al_self = alpha4f[(size_t)(E + n) * 4 + hh];
    // merged online max + denom (lanes stride edges); cache raw alpha in LDS
    float m = al_self, den = 0.f;
    for (int k = rs + c; k < re; k += 64) {
        int kk = k - rs;
        float a = alpha4f[(size_t)csr_eid[k] * 4 + hh];
        if (kk < MAXD) lw[hh][kk] = a;
        float mn = fmaxf(m, a);
        den = den * __expf(m - mn) + __expf(a - mn);
        m = mn;
    }
    #pragma unroll
    for (int off = 32; off; off >>= 1) {
        float m2 = __shfl_xor(m, off, 64);
        float d2 = __shfl_xor(den, off, 64);
        float mn = fmaxf(m, m2);
        den = den * __expf(m - mn) + d2 * __expf(m2 - mn);
        m = mn;
    }
    den += __expf(al_self - m);
    float inv_den = 1.0f / den;
    int cap = min(deg, MAXD);
    for (int kk = c; kk < cap; kk += 64)
        lw[hh][kk] = __expf(lw[hh][kk] - m) * inv_den;
    float acc = __expf(al_self - m) * inv_den * xh[(size_t)n * DD + tid];
    for (int k = rs; k < re; ++k) {
        int kk = k - rs;
        int s = csr_src[k];
        float w = (kk < MAXD) ? lw[hh][kk]
                              : __expf(alpha4f[(size_t)csr_eid[k] * 4 + hh] - m) * inv_den;
        acc += w * xh[(size_t)s * DD + tid];
    }
    float val = acc + gat_b[tid];
    s1[tid] = val;
    s2[tid] = val * val;
    __syncthreads();
    for (int off = 128; off; off >>= 1) {
        if (tid < off) { s1[tid] += s1[tid + off]; s2[tid] += s2[tid + off]; }
        __syncthreads();
    }
    float mu = s1[0] * (1.0f / DD);
    float var = s2[0] * (1.0f / DD) - mu * mu;
    float normed = (val - mu) * rsqrtf(var + 1e-5f) * ln_g[tid] + ln_b[tid];
    h[(size_t)n * DD + tid] += fmaxf(normed, 0.f);
}

// ---------------------------------------------------------------------------
// K7b: gate scalar per node
__global__ __launch_bounds__(256) void gate_kernel(
    const float* __restrict__ hid, const float* __restrict__ w2,
    const float* __restrict__ b2, float* __restrict__ gate, int N) {
    int n = blockIdx.x;
    int tid = threadIdx.x;
    __shared__ float red[256];
    red[tid] = hid[(size_t)n * DD + tid] * w2[tid];
    __syncthreads();
    for (int off = 128; off; off >>= 1) {
        if (tid < off) red[tid] += red[tid + off];
        __syncthreads();
    }
    if (tid == 0) gate[n] = red[0] + b2[0];
}

// K7pre: batch segment boundaries (batch is sorted)
__global__ void bstart_kernel(const int* __restrict__ batch, int* __restrict__ bstart,
                              int N, int B) {
    int b = threadIdx.x;
    if (b > B) return;
    int lo = 0, hi = N;
    while (lo < hi) {
        int mid = (lo + hi) >> 1;
        if (batch[mid] < b) lo = mid + 1; else hi = mid;
    }
    bstart[b] = lo;
}

// K7a: per-graph gate max + denom (B blocks)
__global__ __launch_bounds__(256) void gseg_kernel(
    const float* __restrict__ gate, const int* __restrict__ bstart,
    float* __restrict__ gmax, float* __restrict__ gden) {
    int b = blockIdx.x;
    int tid = threadIdx.x;
    int s0 = bstart[b], s1 = bstart[b + 1];
    __shared__ float red[256];
    float m = -1e30f;
    for (int i = s0 + tid; i < s1; i += 256) m = fmaxf(m, gate[i]);
    red[tid] = m;
    __syncthreads();
    for (int off = 128; off; off >>= 1) {
        if (tid < off) red[tid] = fmaxf(red[tid], red[tid + off]);
        __syncthreads();
    }
    float gm = red[0];
    __syncthreads();
    float s = 0.f;
    for (int i = s0 + tid; i < s1; i += 256) s += __expf(gate[i] - gm);
    red[tid] = s;
    __syncthreads();
    for (int off = 128; off; off >>= 1) {
        if (tid < off) red[tid] += red[tid + off];
        __syncthreads();
    }
    if (tid == 0) {
        gmax[b] = gm;
        gden[b] = red[0];
    }
}

// K7c: per-node pooling weight
__global__ void wgt_kernel(const float* __restrict__ gate, const int* __restrict__ batch,
                           const float* __restrict__ gmax, const float* __restrict__ gden,
                           float* __restrict__ wgt, int N) {
    int n = blockIdx.x * 256 + threadIdx.x;
    if (n >= N) return;
    int b = batch[n];
    wgt[n] = __expf(gate[n] - gmax[b]) / gden[b];
}

// K7d: scatter-accumulate pooled embedding.
#define POOL_CHUNK 32
__global__ __launch_bounds__(256) void pool_scatter_kernel(
    const float* __restrict__ h, const float* __restrict__ wgt,
    const int* __restrict__ batch, float* __restrict__ g_embed, int N) {
    int i0 = blockIdx.x * POOL_CHUNK;
    int d = threadIdx.x;
    int iend = min(i0 + POOL_CHUNK, N);
    float acc = 0.f;
    int cur = batch[i0];
    for (int i = i0; i < iend; ++i) {
        int b = batch[i];
        if (b != cur) {
            atomicAdd(&g_embed[cur * DD + d], acc);
            acc = 0.f;
            cur = b;
        }
        acc += wgt[i] * h[(size_t)i * DD + d];
    }
    atomicAdd(&g_embed[cur * DD + d], acc);
}

// K8: readout MLP [B,256] -> [B,256]
__global__ __launch_bounds__(256) void readout_kernel(
    const float* __restrict__ g_embed, const float* __restrict__ w1,
    const float* __restrict__ b1, const float* __restrict__ w2,
    const float* __restrict__ b2, float* __restrict__ out) {
    int b = blockIdx.x;
    int tid = threadIdx.x;
    __shared__ float gvec[256];
    __shared__ float hid[256];
    gvec[tid] = g_embed[b * DD + tid];
    __syncthreads();
    float hv = b1[tid];
    for (int k = 0; k < DD; ++k) hv += gvec[k] * w1[k * DD + tid];
    hid[tid] = fmaxf(hv, 0.f);
    __syncthreads();
    float o = b2[tid];
    for (int t = 0; t < DD; ++t) o += hid[t] * w2[t * DD + tid];
    out[b * DD + tid] = o;
}

// ---------------------------------------------------------------------------
extern "C" void kernel_launch(void* const* d_in, const int* in_sizes, int n_in,
                              void* d_out, int out_size, void* d_ws, size_t ws_size,
                              hipStream_t stream) {
    const float* x        = (const float*)d_in[0];
    const float* edge_attr= (const float*)d_in[1];
    const int*   edge_idx = (const int*)d_in[2];
    const int*   batch    = (const int*)d_in[3];
    const float* enc_w    = (const float*)d_in[4];
    const float* enc_b    = (const float*)d_in[5];
    const float* eenc_w   = (const float*)d_in[6];
    const float* eenc_b   = (const float*)d_in[7];
    const float* gat_w    = (const float*)d_in[8];
    const float* att_src  = (const float*)d_in[9];
    const float* att_dst  = (const float*)d_in[10];
    const float* att_edge = (const float*)d_in[11];
    const float* gat_ew   = (const float*)d_in[12];
    const float* gat_b    = (const float*)d_in[13];
    const float* ln_g     = (const float*)d_in[14];
    const float* ln_b     = (const float*)d_in[15];
    const float* gate_w1  = (const float*)d_in[16];
    const float* gate_b1  = (const float*)d_in[17];
    const float* gate_w2  = (const float*)d_in[18];
    const float* gate_b2  = (const float*)d_in[19];
    const float* ro_w1    = (const float*)d_in[20];
    const float* ro_b1    = (const float*)d_in[21];
    const float* ro_w2    = (const float*)d_in[22];
    const float* ro_b2    = (const float*)d_in[23];
    float* out = (float*)d_out;

    const int N = in_sizes[0] / 42;       // 10000
    const int E = in_sizes[1] / 12;       // 160000
    const int B = out_size / DD;          // 16

    // workspace carve-up
    char* p = (char*)d_ws;
    auto alloc = [&](size_t bytes) {
        char* r = p;
        p += (bytes + 255) & ~(size_t)255;
        return (void*)r;
    };
    float* h        = (float*)alloc((size_t)N * DD * 4);
    float* xh       = (float*)alloc((size_t)N * DD * 4);
    float* a_s      = (float*)alloc((size_t)N * HH * 4);
    float* a_d      = (float*)alloc((size_t)N * HH * 4);
    float* a_e_all  = (float*)alloc((size_t)(E + N) * LH * 4);  // [e][l*4+h]
    float* alpha4   = (float*)alloc((size_t)(E + N) * 4 * 4);   // [e][4], per-layer reuse
    float* wproj    = (float*)alloc((size_t)DD * LH * 4);
    float* gate     = (float*)alloc((size_t)N * 4);
    float* g_embed  = (float*)alloc((size_t)B * DD * 4);
    float* gmax     = (float*)alloc((size_t)B * 4);
    float* gden     = (float*)alloc((size_t)B * 4);
    float* wgt      = (float*)alloc((size_t)N * 4);
    int* deg        = (int*)alloc((size_t)N * 4);
    int* row_ptr    = (int*)alloc((size_t)(N + 1) * 4);
    int* cursor     = (int*)alloc((size_t)N * 4);
    int* csr_src    = (int*)alloc((size_t)E * 4);
    int* csr_eid    = (int*)alloc((size_t)E * 4);
    int* bstart     = (int*)alloc((size_t)(B + 1) * 4);

    const int* src_arr = edge_idx;
    const int* dst_arr = edge_idx + E;

    hipMemsetAsync(deg, 0, (size_t)N * 4, stream);
    hipMemsetAsync(g_embed, 0, (size_t)B * DD * 4, stream);

    wproj_kernel<<<LL, 256, 0, stream>>>(gat_ew, att_edge, wproj);
    encoder_kernel<<<N, 256, 0, stream>>>(x, enc_w, enc_b, h, N);
    deg_kernel<<<(E + 255) / 256, 256, 0, stream>>>(dst_arr, deg, E);
    scan_kernel<<<1, 1024, 0, stream>>>(deg, row_ptr, N);
    copy_int_kernel<<<(N + 255) / 256, 256, 0, stream>>>(row_ptr, cursor, N);
    scatter_kernel<<<(E + 255) / 256, 256, 0, stream>>>(
        src_arr, dst_arr, cursor, csr_src, csr_eid, E);
    edge_pre_kernel<<<(E + 255) / 256, 256, 0, stream>>>(
        edge_attr, eenc_w, eenc_b, wproj, a_e_all, E);
    self_ae_kernel<<<(N * LH + 255) / 256, 256, 0, stream>>>(
        row_ptr, csr_eid, a_e_all, N, E);

    dim3 ggrid((N + 63) / 64, 4);
    for (int l = 0; l < LL; ++l) {
        gemm256_kernel<<<ggrid, 256, 0, stream>>>(
            h, gat_w + (size_t)l * DD * DD, nullptr, xh, N, 0,
            att_src + l * DD, att_dst + l * DD, a_s, a_d);
        alpha_kernel<<<(E + N + 255) / 256, 256, 0, stream>>>(
            a_s, a_d, a_e_all + l * HH, src_arr, dst_arr, (float4*)alpha4, E, N);
        gat_message2_kernel<<<N, 256, 0, stream>>>(
            xh, alpha4, row_ptr, csr_src, csr_eid,
            gat_b + l * DD, ln_g + l * DD, ln_b + l * DD, h, N, E);
    }

    // pooling gate MLP: hidden = relu(h @ gate_w1 + gate_b1) into xh (reuse)
    gemm256_kernel<<<ggrid, 256, 0, stream>>>(h, gate_w1, gate_b1, xh, N, 1,
                                              nullptr, nullptr, nullptr, nullptr);
    gate_kernel<<<N, 256, 0, stream>>>(xh, gate_w2, gate_b2, gate, N);
    bstart_kernel<<<1, 32, 0, stream>>>(batch, bstart, N, B);
    gseg_kernel<<<B, 256, 0, stream>>>(gate, bstart, gmax, gden);
    wgt_kernel<<<(N + 255) / 256, 256, 0, stream>>>(gate, batch, gmax, gden, wgt, N);
    pool_scatter_kernel<<<(N + POOL_CHUNK - 1) / POOL_CHUNK, 256, 0, stream>>>(
        h, wgt, batch, g_embed, N);
    readout_kernel<<<B, 256, 0, stream>>>(g_embed, ro_w1, ro_b1, ro_w2, ro_b2, out);
}

// Round 7
// 690.150 us; speedup vs baseline: 1.2311x; 1.0258x over previous
//
#include <hip/hip_runtime.h>
#include <math.h>

// Problem constants (fixed-shape problem)
#define DD 256
#define HH 4
#define CC 64
#define LL 5
#define NEG_SLOPE 0.2f
#define LH 20   // L*H
#define MAXD 768  // LDS softmax-weight cache cap

static __device__ __forceinline__ float lrelu(float x) {
    return x > 0.0f ? x : NEG_SLOPE * x;
}

// ---------------------------------------------------------------------------
// K0: wproj[k][l*4+h] = sum_c gat_ew[l][k][h*64+c] * att_edge[l][h][c]
__global__ __launch_bounds__(256) void wproj_kernel(
    const float* __restrict__ gat_ew, const float* __restrict__ att_edge,
    float* __restrict__ wproj) {
    int l = blockIdx.x;
    int k = threadIdx.x;
    const float* W = gat_ew + (size_t)l * DD * DD;
    const float* att = att_edge + l * DD;  // [H][C] flat = 256
    for (int hh = 0; hh < HH; ++hh) {
        float s = 0.f;
        #pragma unroll
        for (int c = 0; c < CC; ++c)
            s += W[k * DD + hh * CC + c] * att[hh * CC + c];
        wproj[k * LH + l * HH + hh] = s;
    }
}

// ---------------------------------------------------------------------------
// K1: node encoder h = relu(x @ enc_w + enc_b)
__global__ __launch_bounds__(256) void encoder_kernel(
    const float* __restrict__ x, const float* __restrict__ enc_w,
    const float* __restrict__ enc_b, float* __restrict__ h, int N) {
    int n = blockIdx.x;
    int tid = threadIdx.x;
    __shared__ float xs[42];
    if (tid < 42) xs[tid] = x[(size_t)n * 42 + tid];
    __syncthreads();
    float acc = enc_b[tid];
    #pragma unroll
    for (int f = 0; f < 42; ++f) acc += xs[f] * enc_w[f * DD + tid];
    h[(size_t)n * DD + tid] = fmaxf(acc, 0.f);
}

// ---------------------------------------------------------------------------
// K2: per-edge a_e[e][l*4+h] = relu(edge_attr[e]@eenc_w + eenc_b) . wproj[:,l*4+h]
// 1 edge/thread. Wave-uniform b128 LDS broadcasts as direct float4 temps.
// unroll 2: compiler hoists next-k DS reads behind current-k FMAs (latency
// hiding at low wave count). NOTE: direct temps only — indexed local-array
// staging caused scratch spill in R3.
__global__ __launch_bounds__(256) void edge_pre_kernel(
    const float* __restrict__ edge_attr,
    const float* __restrict__ eenc_w, const float* __restrict__ eenc_b,
    const float* __restrict__ wproj, float* __restrict__ a_e_all, int E) {
    __shared__ float Wt[12 * 256];   // k-major: Wt[k*12+f]
    __shared__ float wpl[256 * LH];  // wpl[k*20+j]
    __shared__ float bs[256];        // eenc_b
    int tid = threadIdx.x;
    for (int i = tid; i < 12 * 256; i += 256) {
        int k = i / 12, f = i % 12;
        Wt[i] = eenc_w[f * 256 + k];
    }
    for (int i = tid; i < 256 * LH; i += 256) wpl[i] = wproj[i];
    bs[tid] = eenc_b[tid];
    __syncthreads();

    int e = blockIdx.x * 256 + tid;
    bool v = e < E;
    float ea[12] = {};
    if (v) {
        const float4* p = (const float4*)(edge_attr + (size_t)e * 12);
        *(float4*)&ea[0] = p[0]; *(float4*)&ea[4] = p[1]; *(float4*)&ea[8] = p[2];
    }
    float4 acc[5];
    #pragma unroll
    for (int q = 0; q < 5; ++q) acc[q] = make_float4(0.f, 0.f, 0.f, 0.f);
    #pragma unroll 2
    for (int k = 0; k < 256; ++k) {
        const float4* wr4 = (const float4*)(Wt + k * 12);
        float4 wa = wr4[0], wb = wr4[1], wc = wr4[2];
        float m0 = bs[k];
        m0 += ea[0] * wa.x + ea[1] * wa.y + ea[2] * wa.z + ea[3] * wa.w
            + ea[4] * wb.x + ea[5] * wb.y + ea[6] * wb.z + ea[7] * wb.w
            + ea[8] * wc.x + ea[9] * wc.y + ea[10] * wc.z + ea[11] * wc.w;
        m0 = fmaxf(m0, 0.f);
        const float4* pr4 = (const float4*)(wpl + k * 20);
        #pragma unroll
        for (int q = 0; q < 5; ++q) {
            float4 p = pr4[q];
            acc[q].x += m0 * p.x; acc[q].y += m0 * p.y;
            acc[q].z += m0 * p.z; acc[q].w += m0 * p.w;
        }
    }
    if (v) {
        float4* o = (float4*)(a_e_all + (size_t)e * LH);
        #pragma unroll
        for (int q = 0; q < 5; ++q) o[q] = acc[q];
    }
}

// ---------------------------------------------------------------------------
// deg histogram
__global__ void deg_kernel(const int* __restrict__ dst, int* __restrict__ deg, int E) {
    int e = blockIdx.x * 256 + threadIdx.x;
    if (e < E) atomicAdd(&deg[dst[e]], 1);
}

// K3: self-loop a_e = mean of incoming real-edge a_e (via CSR, no atomics)
__global__ void self_ae_kernel(const int* __restrict__ row_ptr,
                               const int* __restrict__ csr_eid,
                               float* __restrict__ a_e_all, int N, int E) {
    int i = blockIdx.x * 256 + threadIdx.x;
    if (i >= N * LH) return;
    int n = i / LH;
    int j = i % LH;
    int rs = row_ptr[n], re = row_ptr[n + 1];
    float s = 0.f;
    for (int k = rs; k < re; ++k)
        s += a_e_all[(size_t)csr_eid[k] * LH + j];
    a_e_all[(size_t)(E + n) * LH + j] = s / (float)max(re - rs, 1);
}

// ---------------------------------------------------------------------------
// K4: exclusive prefix scan of deg -> row_ptr  (single block)
__global__ __launch_bounds__(1024) void scan_kernel(const int* __restrict__ deg,
                                                    int* __restrict__ row_ptr, int n) {
    __shared__ int buf[1024];
    __shared__ int carry_s;
    int tid = threadIdx.x;
    if (tid == 0) carry_s = 0;
    __syncthreads();
    for (int base = 0; base < n; base += 1024) {
        int i = base + tid;
        int v = (i < n) ? deg[i] : 0;
        buf[tid] = v;
        __syncthreads();
        for (int off = 1; off < 1024; off <<= 1) {
            int t = (tid >= off) ? buf[tid - off] : 0;
            __syncthreads();
            buf[tid] += t;
            __syncthreads();
        }
        int carry = carry_s;
        if (i < n) row_ptr[i] = carry + buf[tid] - v;
        __syncthreads();
        if (tid == 1023) carry_s = carry + buf[1023];
        __syncthreads();
    }
    if (tid == 0) row_ptr[n] = carry_s;
}

__global__ void copy_int_kernel(const int* __restrict__ a, int* __restrict__ b, int n) {
    int i = blockIdx.x * 256 + threadIdx.x;
    if (i < n) b[i] = a[i];
}

// K4c: scatter edges into CSR order by dst
__global__ void scatter_kernel(const int* __restrict__ src, const int* __restrict__ dst,
                               int* __restrict__ cursor, int* __restrict__ csr_src,
                               int* __restrict__ csr_eid, int E) {
    int e = blockIdx.x * 256 + threadIdx.x;
    if (e >= E) return;
    int d = dst[e];
    int pos = atomicAdd(&cursor[d], 1);
    csr_src[pos] = src[e];
    csr_eid[pos] = e;
}

// ---------------------------------------------------------------------------
// GEMM: C[M,256] = A[M,256] @ W[256,256] (+bias, optional relu). fp32, 64x64 tile.
// Fused epilogue (att_src != nullptr): 64-col tile == one head; computes
// a_s[row][head], a_d[row][head] from acc via LDS reduction.
__global__ __launch_bounds__(256) void gemm256_kernel(
    const float* __restrict__ A, const float* __restrict__ W,
    const float* __restrict__ bias, float* __restrict__ C, int M, int do_relu,
    const float* __restrict__ att_src, const float* __restrict__ att_dst,
    float* __restrict__ a_s, float* __restrict__ a_d) {
    __shared__ float As[16][68];
    __shared__ float Bs[16][68];
    __shared__ float reds[64][17];
    __shared__ float redd[64][17];
    int tid = threadIdx.x;
    int tx = tid & 15, ty = tid >> 4;
    int m0 = blockIdx.x * 64;
    int n0 = blockIdx.y * 64;
    float acc[4][4] = {};
    int arow = tid >> 2, aseg = tid & 3;
    int brow = tid >> 4, bseg = tid & 15;
    for (int k0 = 0; k0 < 256; k0 += 16) {
        float4 av = make_float4(0.f, 0.f, 0.f, 0.f);
        int grow = m0 + arow;
        if (grow < M) av = *(const float4*)(A + (size_t)grow * DD + k0 + aseg * 4);
        As[aseg * 4 + 0][arow] = av.x;
        As[aseg * 4 + 1][arow] = av.y;
        As[aseg * 4 + 2][arow] = av.z;
        As[aseg * 4 + 3][arow] = av.w;
        float4 bv = *(const float4*)(W + (size_t)(k0 + brow) * DD + n0 + bseg * 4);
        *(float4*)&Bs[brow][bseg * 4] = bv;
        __syncthreads();
        #pragma unroll
        for (int kk = 0; kk < 16; ++kk) {
            float a0 = As[kk][ty * 4 + 0], a1 = As[kk][ty * 4 + 1];
            float a2 = As[kk][ty * 4 + 2], a3 = As[kk][ty * 4 + 3];
            float b0 = Bs[kk][tx * 4 + 0], b1 = Bs[kk][tx * 4 + 1];
            float b2 = Bs[kk][tx * 4 + 2], b3 = Bs[kk][tx * 4 + 3];
            acc[0][0] += a0 * b0; acc[0][1] += a0 * b1; acc[0][2] += a0 * b2; acc[0][3] += a0 * b3;
            acc[1][0] += a1 * b0; acc[1][1] += a1 * b1; acc[1][2] += a1 * b2; acc[1][3] += a1 * b3;
            acc[2][0] += a2 * b0; acc[2][1] += a2 * b1; acc[2][2] += a2 * b2; acc[2][3] += a2 * b3;
            acc[3][0] += a3 * b0; acc[3][1] += a3 * b1; acc[3][2] += a3 * b2; acc[3][3] += a3 * b3;
        }
        __syncthreads();
    }
    #pragma unroll
    for (int i = 0; i < 4; ++i) {
        int r = m0 + ty * 4 + i;
        if (r >= M) continue;
        #pragma unroll
        for (int j = 0; j < 4; ++j) {
            int col = n0 + tx * 4 + j;
            float v = acc[i][j];
            if (bias) v += bias[col];
            if (do_relu) v = fmaxf(v, 0.f);
            C[(size_t)r * DD + col] = v;
        }
    }
    if (att_src) {
        float ps[4] = {}, pd[4] = {};
        #pragma unroll
        for (int j = 0; j < 4; ++j) {
            float ws = att_src[n0 + tx * 4 + j];
            float wd = att_dst[n0 + tx * 4 + j];
            #pragma unroll
            for (int i = 0; i < 4; ++i) {
                ps[i] += acc[i][j] * ws;
                pd[i] += acc[i][j] * wd;
            }
        }
        #pragma unroll
        for (int i = 0; i < 4; ++i) {
            reds[ty * 4 + i][tx] = ps[i];
            redd[ty * 4 + i][tx] = pd[i];
        }
        __syncthreads();
        if (tid < 64) {
            float ss = 0.f, sd = 0.f;
            #pragma unroll
            for (int t = 0; t < 16; ++t) { ss += reds[tid][t]; sd += redd[tid][t]; }
            int r = m0 + tid;
            if (r < M) {
                a_s[r * HH + blockIdx.y] = ss;
                a_d[r * HH + blockIdx.y] = sd;
            }
        }
    }
}

// ---------------------------------------------------------------------------
// K6: fused alpha + softmax attention + aggregation + bias + LN + relu + residual.
// alpha computed inline (a_d[n] wave-uniform; a_s/a_e gathered once, cached in
// LDS with csr_src). One barrier publishes lsrc (wave 0) to all waves.
__global__ __launch_bounds__(256) void gat_message3_kernel(
    const float* __restrict__ xh, const float* __restrict__ a_s,
    const float* __restrict__ a_d, const float* __restrict__ a_e,  // + l*4; [e][20]
    const int* __restrict__ row_ptr, const int* __restrict__ csr_src,
    const int* __restrict__ csr_eid, const float* __restrict__ gat_b,
    const float* __restrict__ ln_g, const float* __restrict__ ln_b,
    float* __restrict__ h, int N, int E) {
    __shared__ float lw[4][MAXD];   // 12 KB softmax weights
    __shared__ int lsrc[MAXD];      // 3 KB src cache
    __shared__ float s1[256], s2[256];
    int n = blockIdx.x;
    int tid = threadIdx.x;
    int hh = tid >> 6, c = tid & 63;
    int rs = row_ptr[n], re = row_ptr[n + 1];
    int deg = re - rs;
    float adn = a_d[n * HH + hh];
    float al_self = lrelu(a_s[n * HH + hh] + adn + a_e[(size_t)(E + n) * LH + hh]);
    // pass 1: merged online max+denom; compute alpha inline, cache in LDS
    float m = al_self, den = 0.f;
    for (int k = rs + c; k < re; k += 64) {
        int kk = k - rs;
        int s = csr_src[k];
        int eid = csr_eid[k];
        float a = lrelu(a_s[s * HH + hh] + adn + a_e[(size_t)eid * LH + hh]);
        if (kk < MAXD) {
            lw[hh][kk] = a;
            if (hh == 0) lsrc[kk] = s;
        }
        float mn = fmaxf(m, a);
        den = den * __expf(m - mn) + __expf(a - mn);
        m = mn;
    }
    #pragma unroll
    for (int off = 32; off; off >>= 1) {
        float m2 = __shfl_xor(m, off, 64);
        float d2 = __shfl_xor(den, off, 64);
        float mn = fmaxf(m, m2);
        den = den * __expf(m - mn) + d2 * __expf(m2 - mn);
        m = mn;
    }
    den += __expf(al_self - m);
    float inv_den = 1.0f / den;
    // convert cached alpha -> softmax weight (wave-private rows)
    int cap = min(deg, MAXD);
    for (int kk = c; kk < cap; kk += 64)
        lw[hh][kk] = __expf(lw[hh][kk] - m) * inv_den;
    __syncthreads();  // publish lsrc (wave 0) to all waves
    // pass 3: aggregation; weights + src via LDS broadcast, xh rows coalesced
    float acc = __expf(al_self - m) * inv_den * xh[(size_t)n * DD + tid];
    for (int k = rs; k < re; ++k) {
        int kk = k - rs;
        int s;
        float w;
        if (kk < MAXD) { s = lsrc[kk]; w = lw[hh][kk]; }
        else {
            s = csr_src[k];
            float a = lrelu(a_s[s * HH + hh] + adn + a_e[(size_t)csr_eid[k] * LH + hh]);
            w = __expf(a - m) * inv_den;
        }
        acc += w * xh[(size_t)s * DD + tid];
    }
    float val = acc + gat_b[tid];
    s1[tid] = val;
    s2[tid] = val * val;
    __syncthreads();
    for (int off = 128; off; off >>= 1) {
        if (tid < off) { s1[tid] += s1[tid + off]; s2[tid] += s2[tid + off]; }
        __syncthreads();
    }
    float mu = s1[0] * (1.0f / DD);
    float var = s2[0] * (1.0f / DD) - mu * mu;
    float normed = (val - mu) * rsqrtf(var + 1e-5f) * ln_g[tid] + ln_b[tid];
    h[(size_t)n * DD + tid] += fmaxf(normed, 0.f);
}

// ---------------------------------------------------------------------------
// K7b: gate scalar per node
__global__ __launch_bounds__(256) void gate_kernel(
    const float* __restrict__ hid, const float* __restrict__ w2,
    const float* __restrict__ b2, float* __restrict__ gate, int N) {
    int n = blockIdx.x;
    int tid = threadIdx.x;
    __shared__ float red[256];
    red[tid] = hid[(size_t)n * DD + tid] * w2[tid];
    __syncthreads();
    for (int off = 128; off; off >>= 1) {
        if (tid < off) red[tid] += red[tid + off];
        __syncthreads();
    }
    if (tid == 0) gate[n] = red[0] + b2[0];
}

// K7pre: batch segment boundaries (batch is sorted)
__global__ void bstart_kernel(const int* __restrict__ batch, int* __restrict__ bstart,
                              int N, int B) {
    int b = threadIdx.x;
    if (b > B) return;
    int lo = 0, hi = N;
    while (lo < hi) {
        int mid = (lo + hi) >> 1;
        if (batch[mid] < b) lo = mid + 1; else hi = mid;
    }
    bstart[b] = lo;
}

// K7a: per-graph gate max + denom (B blocks)
__global__ __launch_bounds__(256) void gseg_kernel(
    const float* __restrict__ gate, const int* __restrict__ bstart,
    float* __restrict__ gmax, float* __restrict__ gden) {
    int b = blockIdx.x;
    int tid = threadIdx.x;
    int s0 = bstart[b], s1 = bstart[b + 1];
    __shared__ float red[256];
    float m = -1e30f;
    for (int i = s0 + tid; i < s1; i += 256) m = fmaxf(m, gate[i]);
    red[tid] = m;
    __syncthreads();
    for (int off = 128; off; off >>= 1) {
        if (tid < off) red[tid] = fmaxf(red[tid], red[tid + off]);
        __syncthreads();
    }
    float gm = red[0];
    __syncthreads();
    float s = 0.f;
    for (int i = s0 + tid; i < s1; i += 256) s += __expf(gate[i] - gm);
    red[tid] = s;
    __syncthreads();
    for (int off = 128; off; off >>= 1) {
        if (tid < off) red[tid] += red[tid + off];
        __syncthreads();
    }
    if (tid == 0) {
        gmax[b] = gm;
        gden[b] = red[0];
    }
}

// K7c: per-node pooling weight
__global__ void wgt_kernel(const float* __restrict__ gate, const int* __restrict__ batch,
                           const float* __restrict__ gmax, const float* __restrict__ gden,
                           float* __restrict__ wgt, int N) {
    int n = blockIdx.x * 256 + threadIdx.x;
    if (n >= N) return;
    int b = batch[n];
    wgt[n] = __expf(gate[n] - gmax[b]) / gden[b];
}

// K7d: scatter-accumulate pooled embedding.
#define POOL_CHUNK 32
__global__ __launch_bounds__(256) void pool_scatter_kernel(
    const float* __restrict__ h, const float* __restrict__ wgt,
    const int* __restrict__ batch, float* __restrict__ g_embed, int N) {
    int i0 = blockIdx.x * POOL_CHUNK;
    int d = threadIdx.x;
    int iend = min(i0 + POOL_CHUNK, N);
    float acc = 0.f;
    int cur = batch[i0];
    for (int i = i0; i < iend; ++i) {
        int b = batch[i];
        if (b != cur) {
            atomicAdd(&g_embed[cur * DD + d], acc);
            acc = 0.f;
            cur = b;
        }
        acc += wgt[i] * h[(size_t)i * DD + d];
    }
    atomicAdd(&g_embed[cur * DD + d], acc);
}

// K8: readout MLP [B,256] -> [B,256]
__global__ __launch_bounds__(256) void readout_kernel(
    const float* __restrict__ g_embed, const float* __restrict__ w1,
    const float* __restrict__ b1, const float* __restrict__ w2,
    const float* __restrict__ b2, float* __restrict__ out) {
    int b = blockIdx.x;
    int tid = threadIdx.x;
    __shared__ float gvec[256];
    __shared__ float hid[256];
    gvec[tid] = g_embed[b * DD + tid];
    __syncthreads();
    float hv = b1[tid];
    for (int k = 0; k < DD; ++k) hv += gvec[k] * w1[k * DD + tid];
    hid[tid] = fmaxf(hv, 0.f);
    __syncthreads();
    float o = b2[tid];
    for (int t = 0; t < DD; ++t) o += hid[t] * w2[t * DD + tid];
    out[b * DD + tid] = o;
}

// ---------------------------------------------------------------------------
extern "C" void kernel_launch(void* const* d_in, const int* in_sizes, int n_in,
                              void* d_out, int out_size, void* d_ws, size_t ws_size,
                              hipStream_t stream) {
    const float* x        = (const float*)d_in[0];
    const float* edge_attr= (const float*)d_in[1];
    const int*   edge_idx = (const int*)d_in[2];
    const int*   batch    = (const int*)d_in[3];
    const float* enc_w    = (const float*)d_in[4];
    const float* enc_b    = (const float*)d_in[5];
    const float* eenc_w   = (const float*)d_in[6];
    const float* eenc_b   = (const float*)d_in[7];
    const float* gat_w    = (const float*)d_in[8];
    const float* att_src  = (const float*)d_in[9];
    const float* att_dst  = (const float*)d_in[10];
    const float* att_edge = (const float*)d_in[11];
    const float* gat_ew   = (const float*)d_in[12];
    const float* gat_b    = (const float*)d_in[13];
    const float* ln_g     = (const float*)d_in[14];
    const float* ln_b     = (const float*)d_in[15];
    const float* gate_w1  = (const float*)d_in[16];
    const float* gate_b1  = (const float*)d_in[17];
    const float* gate_w2  = (const float*)d_in[18];
    const float* gate_b2  = (const float*)d_in[19];
    const float* ro_w1    = (const float*)d_in[20];
    const float* ro_b1    = (const float*)d_in[21];
    const float* ro_w2    = (const float*)d_in[22];
    const float* ro_b2    = (const float*)d_in[23];
    float* out = (float*)d_out;

    const int N = in_sizes[0] / 42;       // 10000
    const int E = in_sizes[1] / 12;       // 160000
    const int B = out_size / DD;          // 16

    // workspace carve-up
    char* p = (char*)d_ws;
    auto alloc = [&](size_t bytes) {
        char* r = p;
        p += (bytes + 255) & ~(size_t)255;
        return (void*)r;
    };
    float* h        = (float*)alloc((size_t)N * DD * 4);
    float* xh       = (float*)alloc((size_t)N * DD * 4);
    float* a_s      = (float*)alloc((size_t)N * HH * 4);
    float* a_d      = (float*)alloc((size_t)N * HH * 4);
    float* a_e_all  = (float*)alloc((size_t)(E + N) * LH * 4);  // [e][l*4+h]
    float* wproj    = (float*)alloc((size_t)DD * LH * 4);
    float* gate     = (float*)alloc((size_t)N * 4);
    float* g_embed  = (float*)alloc((size_t)B * DD * 4);
    float* gmax     = (float*)alloc((size_t)B * 4);
    float* gden     = (float*)alloc((size_t)B * 4);
    float* wgt      = (float*)alloc((size_t)N * 4);
    int* deg        = (int*)alloc((size_t)N * 4);
    int* row_ptr    = (int*)alloc((size_t)(N + 1) * 4);
    int* cursor     = (int*)alloc((size_t)N * 4);
    int* csr_src    = (int*)alloc((size_t)E * 4);
    int* csr_eid    = (int*)alloc((size_t)E * 4);
    int* bstart     = (int*)alloc((size_t)(B + 1) * 4);

    const int* src_arr = edge_idx;
    const int* dst_arr = edge_idx + E;

    hipMemsetAsync(deg, 0, (size_t)N * 4, stream);
    hipMemsetAsync(g_embed, 0, (size_t)B * DD * 4, stream);

    wproj_kernel<<<LL, 256, 0, stream>>>(gat_ew, att_edge, wproj);
    encoder_kernel<<<N, 256, 0, stream>>>(x, enc_w, enc_b, h, N);
    deg_kernel<<<(E + 255) / 256, 256, 0, stream>>>(dst_arr, deg, E);
    scan_kernel<<<1, 1024, 0, stream>>>(deg, row_ptr, N);
    copy_int_kernel<<<(N + 255) / 256, 256, 0, stream>>>(row_ptr, cursor, N);
    scatter_kernel<<<(E + 255) / 256, 256, 0, stream>>>(
        src_arr, dst_arr, cursor, csr_src, csr_eid, E);
    edge_pre_kernel<<<(E + 255) / 256, 256, 0, stream>>>(
        edge_attr, eenc_w, eenc_b, wproj, a_e_all, E);
    self_ae_kernel<<<(N * LH + 255) / 256, 256, 0, stream>>>(
        row_ptr, csr_eid, a_e_all, N, E);

    dim3 ggrid((N + 63) / 64, 4);
    for (int l = 0; l < LL; ++l) {
        gemm256_kernel<<<ggrid, 256, 0, stream>>>(
            h, gat_w + (size_t)l * DD * DD, nullptr, xh, N, 0,
            att_src + l * DD, att_dst + l * DD, a_s, a_d);
        gat_message3_kernel<<<N, 256, 0, stream>>>(
            xh, a_s, a_d, a_e_all + l * HH, row_ptr, csr_src, csr_eid,
            gat_b + l * DD, ln_g + l * DD, ln_b + l * DD, h, N, E);
    }

    // pooling gate MLP: hidden = relu(h @ gate_w1 + gate_b1) into xh (reuse)
    gemm256_kernel<<<ggrid, 256, 0, stream>>>(h, gate_w1, gate_b1, xh, N, 1,
                                              nullptr, nullptr, nullptr, nullptr);
    gate_kernel<<<N, 256, 0, stream>>>(xh, gate_w2, gate_b2, gate, N);
    bstart_kernel<<<1, 32, 0, stream>>>(batch, bstart, N, B);
    gseg_kernel<<<B, 256, 0, stream>>>(gate, bstart, gmax, gden);
    wgt_kernel<<<(N + 255) / 256, 256, 0, stream>>>(gate, batch, gmax, gden, wgt, N);
    pool_scatter_kernel<<<(N + POOL_CHUNK - 1) / POOL_CHUNK, 256, 0, stream>>>(
        h, wgt, batch, g_embed, N);
    readout_kernel<<<B, 256, 0, stream>>>(g_embed, ro_w1, ro_b1, ro_w2, ro_b2, out);
}

// Round 8
// 658.843 us; speedup vs baseline: 1.2896x; 1.0475x over previous
//
#include <hip/hip_runtime.h>
#include <math.h>

// Problem constants (fixed-shape problem)
#define DD 256
#define HH 4
#define CC 64
#define LL 5
#define NEG_SLOPE 0.2f
#define LH 20   // L*H
#define MAXD 768  // LDS softmax-weight cache cap

static __device__ __forceinline__ float lrelu(float x) {
    return x > 0.0f ? x : NEG_SLOPE * x;
}

// ---------------------------------------------------------------------------
// K0: wproj[k][l*4+h] = sum_c gat_ew[l][k][h*64+c] * att_edge[l][h][c]
__global__ __launch_bounds__(256) void wproj_kernel(
    const float* __restrict__ gat_ew, const float* __restrict__ att_edge,
    float* __restrict__ wproj) {
    int l = blockIdx.x;
    int k = threadIdx.x;
    const float* W = gat_ew + (size_t)l * DD * DD;
    const float* att = att_edge + l * DD;  // [H][C] flat = 256
    for (int hh = 0; hh < HH; ++hh) {
        float s = 0.f;
        #pragma unroll
        for (int c = 0; c < CC; ++c)
            s += W[k * DD + hh * CC + c] * att[hh * CC + c];
        wproj[k * LH + l * HH + hh] = s;
    }
}

// K0b: pack per-k weights contiguous: wpack[k][0..11]=Wt row, [12..31]=wproj row,
// [32]=eenc_b, [33..35] pad. 144B per k, 16B aligned.
__global__ __launch_bounds__(256) void wpack_kernel(
    const float* __restrict__ eenc_w, const float* __restrict__ eenc_b,
    const float* __restrict__ wproj, float* __restrict__ wpack) {
    int k = threadIdx.x;
    #pragma unroll
    for (int f = 0; f < 12; ++f) wpack[k * 36 + f] = eenc_w[f * 256 + k];
    #pragma unroll
    for (int j = 0; j < 20; ++j) wpack[k * 36 + 12 + j] = wproj[k * LH + j];
    wpack[k * 36 + 32] = eenc_b[k];
    wpack[k * 36 + 33] = 0.f; wpack[k * 36 + 34] = 0.f; wpack[k * 36 + 35] = 0.f;
}

// ---------------------------------------------------------------------------
// K1: node encoder h = relu(x @ enc_w + enc_b)
__global__ __launch_bounds__(256) void encoder_kernel(
    const float* __restrict__ x, const float* __restrict__ enc_w,
    const float* __restrict__ enc_b, float* __restrict__ h, int N) {
    int n = blockIdx.x;
    int tid = threadIdx.x;
    __shared__ float xs[42];
    if (tid < 42) xs[tid] = x[(size_t)n * 42 + tid];
    __syncthreads();
    float acc = enc_b[tid];
    #pragma unroll
    for (int f = 0; f < 42; ++f) acc += xs[f] * enc_w[f * DD + tid];
    h[(size_t)n * DD + tid] = fmaxf(acc, 0.f);
}

// ---------------------------------------------------------------------------
// K2: per-edge a_e[e][l*4+h] = relu(edge_attr[e]@eenc_w + eenc_b) . wproj[:,l*4+h]
// 1 edge/thread. Weights via wave-uniform global_load_dwordx4 (VMEM broadcast,
// L1/L2-resident wpack) — zero DS-pipe traffic; kernel is VALU-bound.
__global__ __launch_bounds__(256) void edge_pre_kernel(
    const float* __restrict__ edge_attr, const float* __restrict__ wpack,
    float* __restrict__ a_e_all, int E) {
    int tid = threadIdx.x;
    int e = blockIdx.x * 256 + tid;
    bool v = e < E;
    float ea[12] = {};
    if (v) {
        const float4* p = (const float4*)(edge_attr + (size_t)e * 12);
        *(float4*)&ea[0] = p[0]; *(float4*)&ea[4] = p[1]; *(float4*)&ea[8] = p[2];
    }
    float4 acc[5];
    #pragma unroll
    for (int q = 0; q < 5; ++q) acc[q] = make_float4(0.f, 0.f, 0.f, 0.f);
    for (int k = 0; k < 256; ++k) {
        const float4* wp = (const float4*)(wpack + k * 36);
        float4 wa = wp[0], wb = wp[1], wc = wp[2];
        float4 wt = wp[8];  // .x = bias
        float m0 = wt.x;
        m0 += ea[0] * wa.x + ea[1] * wa.y + ea[2] * wa.z + ea[3] * wa.w
            + ea[4] * wb.x + ea[5] * wb.y + ea[6] * wb.z + ea[7] * wb.w
            + ea[8] * wc.x + ea[9] * wc.y + ea[10] * wc.z + ea[11] * wc.w;
        m0 = fmaxf(m0, 0.f);
        float4 p0 = wp[3], p1 = wp[4], p2 = wp[5], p3 = wp[6], p4 = wp[7];
        acc[0].x += m0 * p0.x; acc[0].y += m0 * p0.y; acc[0].z += m0 * p0.z; acc[0].w += m0 * p0.w;
        acc[1].x += m0 * p1.x; acc[1].y += m0 * p1.y; acc[1].z += m0 * p1.z; acc[1].w += m0 * p1.w;
        acc[2].x += m0 * p2.x; acc[2].y += m0 * p2.y; acc[2].z += m0 * p2.z; acc[2].w += m0 * p2.w;
        acc[3].x += m0 * p3.x; acc[3].y += m0 * p3.y; acc[3].z += m0 * p3.z; acc[3].w += m0 * p3.w;
        acc[4].x += m0 * p4.x; acc[4].y += m0 * p4.y; acc[4].z += m0 * p4.z; acc[4].w += m0 * p4.w;
    }
    if (v) {
        float4* o = (float4*)(a_e_all + (size_t)e * LH);
        #pragma unroll
        for (int q = 0; q < 5; ++q) o[q] = acc[q];
    }
}

// ---------------------------------------------------------------------------
// deg histogram
__global__ void deg_kernel(const int* __restrict__ dst, int* __restrict__ deg, int E) {
    int e = blockIdx.x * 256 + threadIdx.x;
    if (e < E) atomicAdd(&deg[dst[e]], 1);
}

// K3: self-loop a_e = mean of incoming real-edge a_e (via CSR, no atomics)
__global__ void self_ae_kernel(const int* __restrict__ row_ptr,
                               const int* __restrict__ csr_eid,
                               float* __restrict__ a_e_all, int N, int E) {
    int i = blockIdx.x * 256 + threadIdx.x;
    if (i >= N * LH) return;
    int n = i / LH;
    int j = i % LH;
    int rs = row_ptr[n], re = row_ptr[n + 1];
    float s = 0.f;
    for (int k = rs; k < re; ++k)
        s += a_e_all[(size_t)csr_eid[k] * LH + j];
    a_e_all[(size_t)(E + n) * LH + j] = s / (float)max(re - rs, 1);
}

// ---------------------------------------------------------------------------
// K4: exclusive prefix scan of deg -> row_ptr  (single block)
__global__ __launch_bounds__(1024) void scan_kernel(const int* __restrict__ deg,
                                                    int* __restrict__ row_ptr, int n) {
    __shared__ int buf[1024];
    __shared__ int carry_s;
    int tid = threadIdx.x;
    if (tid == 0) carry_s = 0;
    __syncthreads();
    for (int base = 0; base < n; base += 1024) {
        int i = base + tid;
        int v = (i < n) ? deg[i] : 0;
        buf[tid] = v;
        __syncthreads();
        for (int off = 1; off < 1024; off <<= 1) {
            int t = (tid >= off) ? buf[tid - off] : 0;
            __syncthreads();
            buf[tid] += t;
            __syncthreads();
        }
        int carry = carry_s;
        if (i < n) row_ptr[i] = carry + buf[tid] - v;
        __syncthreads();
        if (tid == 1023) carry_s = carry + buf[1023];
        __syncthreads();
    }
    if (tid == 0) row_ptr[n] = carry_s;
}

__global__ void copy_int_kernel(const int* __restrict__ a, int* __restrict__ b, int n) {
    int i = blockIdx.x * 256 + threadIdx.x;
    if (i < n) b[i] = a[i];
}

// K4c: scatter edges into CSR order by dst
__global__ void scatter_kernel(const int* __restrict__ src, const int* __restrict__ dst,
                               int* __restrict__ cursor, int* __restrict__ csr_src,
                               int* __restrict__ csr_eid, int E) {
    int e = blockIdx.x * 256 + threadIdx.x;
    if (e >= E) return;
    int d = dst[e];
    int pos = atomicAdd(&cursor[d], 1);
    csr_src[pos] = src[e];
    csr_eid[pos] = e;
}

// ---------------------------------------------------------------------------
// GEMM: C[M,256] = A[M,256] @ W[256,256] (+bias, optional relu). fp32, 64x64 tile.
// Inner loop uses explicit 16B-aligned float4 LDS reads (ds_read_b128: 2/kk
// instead of up to 8 b32 — DS-pipe was the limiter). Fused epilogue
// (att_src != nullptr): 64-col tile == one head; computes a_s/a_d from acc.
__global__ __launch_bounds__(256) void gemm256_kernel(
    const float* __restrict__ A, const float* __restrict__ W,
    const float* __restrict__ bias, float* __restrict__ C, int M, int do_relu,
    const float* __restrict__ att_src, const float* __restrict__ att_dst,
    float* __restrict__ a_s, float* __restrict__ a_d) {
    __shared__ __align__(16) float As[16][68];
    __shared__ __align__(16) float Bs[16][68];
    __shared__ float reds[64][17];
    __shared__ float redd[64][17];
    int tid = threadIdx.x;
    int tx = tid & 15, ty = tid >> 4;
    int m0 = blockIdx.x * 64;
    int n0 = blockIdx.y * 64;
    float acc[4][4] = {};
    int arow = tid >> 2, aseg = tid & 3;
    int brow = tid >> 4, bseg = tid & 15;
    for (int k0 = 0; k0 < 256; k0 += 16) {
        float4 av = make_float4(0.f, 0.f, 0.f, 0.f);
        int grow = m0 + arow;
        if (grow < M) av = *(const float4*)(A + (size_t)grow * DD + k0 + aseg * 4);
        As[aseg * 4 + 0][arow] = av.x;
        As[aseg * 4 + 1][arow] = av.y;
        As[aseg * 4 + 2][arow] = av.z;
        As[aseg * 4 + 3][arow] = av.w;
        float4 bv = *(const float4*)(W + (size_t)(k0 + brow) * DD + n0 + bseg * 4);
        *(float4*)&Bs[brow][bseg * 4] = bv;
        __syncthreads();
        #pragma unroll
        for (int kk = 0; kk < 16; ++kk) {
            float4 a4 = *(const float4*)&As[kk][ty * 4];
            float4 b4 = *(const float4*)&Bs[kk][tx * 4];
            acc[0][0] += a4.x * b4.x; acc[0][1] += a4.x * b4.y; acc[0][2] += a4.x * b4.z; acc[0][3] += a4.x * b4.w;
            acc[1][0] += a4.y * b4.x; acc[1][1] += a4.y * b4.y; acc[1][2] += a4.y * b4.z; acc[1][3] += a4.y * b4.w;
            acc[2][0] += a4.z * b4.x; acc[2][1] += a4.z * b4.y; acc[2][2] += a4.z * b4.z; acc[2][3] += a4.z * b4.w;
            acc[3][0] += a4.w * b4.x; acc[3][1] += a4.w * b4.y; acc[3][2] += a4.w * b4.z; acc[3][3] += a4.w * b4.w;
        }
        __syncthreads();
    }
    #pragma unroll
    for (int i = 0; i < 4; ++i) {
        int r = m0 + ty * 4 + i;
        if (r >= M) continue;
        float4 vv;
        int colb = n0 + tx * 4;
        vv.x = acc[i][0]; vv.y = acc[i][1]; vv.z = acc[i][2]; vv.w = acc[i][3];
        if (bias) {
            vv.x += bias[colb + 0]; vv.y += bias[colb + 1];
            vv.z += bias[colb + 2]; vv.w += bias[colb + 3];
        }
        if (do_relu) {
            vv.x = fmaxf(vv.x, 0.f); vv.y = fmaxf(vv.y, 0.f);
            vv.z = fmaxf(vv.z, 0.f); vv.w = fmaxf(vv.w, 0.f);
        }
        *(float4*)(C + (size_t)r * DD + colb) = vv;
    }
    if (att_src) {
        float ps[4] = {}, pd[4] = {};
        #pragma unroll
        for (int j = 0; j < 4; ++j) {
            float ws = att_src[n0 + tx * 4 + j];
            float wd = att_dst[n0 + tx * 4 + j];
            #pragma unroll
            for (int i = 0; i < 4; ++i) {
                ps[i] += acc[i][j] * ws;
                pd[i] += acc[i][j] * wd;
            }
        }
        #pragma unroll
        for (int i = 0; i < 4; ++i) {
            reds[ty * 4 + i][tx] = ps[i];
            redd[ty * 4 + i][tx] = pd[i];
        }
        __syncthreads();
        if (tid < 64) {
            float ss = 0.f, sd = 0.f;
            #pragma unroll
            for (int t = 0; t < 16; ++t) { ss += reds[tid][t]; sd += redd[tid][t]; }
            int r = m0 + tid;
            if (r < M) {
                a_s[r * HH + blockIdx.y] = ss;
                a_d[r * HH + blockIdx.y] = sd;
            }
        }
    }
}

// ---------------------------------------------------------------------------
// K6: fused alpha + softmax attention + aggregation + bias + LN + relu + residual.
__global__ __launch_bounds__(256) void gat_message3_kernel(
    const float* __restrict__ xh, const float* __restrict__ a_s,
    const float* __restrict__ a_d, const float* __restrict__ a_e,  // + l*4; [e][20]
    const int* __restrict__ row_ptr, const int* __restrict__ csr_src,
    const int* __restrict__ csr_eid, const float* __restrict__ gat_b,
    const float* __restrict__ ln_g, const float* __restrict__ ln_b,
    float* __restrict__ h, int N, int E) {
    __shared__ float lw[4][MAXD];   // 12 KB softmax weights
    __shared__ int lsrc[MAXD];      // 3 KB src cache
    __shared__ float s1[256], s2[256];
    int n = blockIdx.x;
    int tid = threadIdx.x;
    int hh = tid >> 6, c = tid & 63;
    int rs = row_ptr[n], re = row_ptr[n + 1];
    int deg = re - rs;
    float adn = a_d[n * HH + hh];
    float al_self = lrelu(a_s[n * HH + hh] + adn + a_e[(size_t)(E + n) * LH + hh]);
    // pass 1: merged online max+denom; compute alpha inline, cache in LDS
    float m = al_self, den = 0.f;
    for (int k = rs + c; k < re; k += 64) {
        int kk = k - rs;
        int s = csr_src[k];
        int eid = csr_eid[k];
        float a = lrelu(a_s[s * HH + hh] + adn + a_e[(size_t)eid * LH + hh]);
        if (kk < MAXD) {
            lw[hh][kk] = a;
            if (hh == 0) lsrc[kk] = s;
        }
        float mn = fmaxf(m, a);
        den = den * __expf(m - mn) + __expf(a - mn);
        m = mn;
    }
    #pragma unroll
    for (int off = 32; off; off >>= 1) {
        float m2 = __shfl_xor(m, off, 64);
        float d2 = __shfl_xor(den, off, 64);
        float mn = fmaxf(m, m2);
        den = den * __expf(m - mn) + d2 * __expf(m2 - mn);
        m = mn;
    }
    den += __expf(al_self - m);
    float inv_den = 1.0f / den;
    // convert cached alpha -> softmax weight (wave-private rows)
    int cap = min(deg, MAXD);
    for (int kk = c; kk < cap; kk += 64)
        lw[hh][kk] = __expf(lw[hh][kk] - m) * inv_den;
    __syncthreads();  // publish lsrc (wave 0) to all waves
    // pass 3: aggregation; weights + src via LDS broadcast, xh rows coalesced
    float acc = __expf(al_self - m) * inv_den * xh[(size_t)n * DD + tid];
    for (int k = rs; k < re; ++k) {
        int kk = k - rs;
        int s;
        float w;
        if (kk < MAXD) { s = lsrc[kk]; w = lw[hh][kk]; }
        else {
            s = csr_src[k];
            float a = lrelu(a_s[s * HH + hh] + adn + a_e[(size_t)csr_eid[k] * LH + hh]);
            w = __expf(a - m) * inv_den;
        }
        acc += w * xh[(size_t)s * DD + tid];
    }
    float val = acc + gat_b[tid];
    s1[tid] = val;
    s2[tid] = val * val;
    __syncthreads();
    for (int off = 128; off; off >>= 1) {
        if (tid < off) { s1[tid] += s1[tid + off]; s2[tid] += s2[tid + off]; }
        __syncthreads();
    }
    float mu = s1[0] * (1.0f / DD);
    float var = s2[0] * (1.0f / DD) - mu * mu;
    float normed = (val - mu) * rsqrtf(var + 1e-5f) * ln_g[tid] + ln_b[tid];
    h[(size_t)n * DD + tid] += fmaxf(normed, 0.f);
}

// ---------------------------------------------------------------------------
// K7b: gate scalar per node
__global__ __launch_bounds__(256) void gate_kernel(
    const float* __restrict__ hid, const float* __restrict__ w2,
    const float* __restrict__ b2, float* __restrict__ gate, int N) {
    int n = blockIdx.x;
    int tid = threadIdx.x;
    __shared__ float red[256];
    red[tid] = hid[(size_t)n * DD + tid] * w2[tid];
    __syncthreads();
    for (int off = 128; off; off >>= 1) {
        if (tid < off) red[tid] += red[tid + off];
        __syncthreads();
    }
    if (tid == 0) gate[n] = red[0] + b2[0];
}

// K7pre: batch segment boundaries (batch is sorted)
__global__ void bstart_kernel(const int* __restrict__ batch, int* __restrict__ bstart,
                              int N, int B) {
    int b = threadIdx.x;
    if (b > B) return;
    int lo = 0, hi = N;
    while (lo < hi) {
        int mid = (lo + hi) >> 1;
        if (batch[mid] < b) lo = mid + 1; else hi = mid;
    }
    bstart[b] = lo;
}

// K7a: per-graph gate max + denom (B blocks)
__global__ __launch_bounds__(256) void gseg_kernel(
    const float* __restrict__ gate, const int* __restrict__ bstart,
    float* __restrict__ gmax, float* __restrict__ gden) {
    int b = blockIdx.x;
    int tid = threadIdx.x;
    int s0 = bstart[b], s1 = bstart[b + 1];
    __shared__ float red[256];
    float m = -1e30f;
    for (int i = s0 + tid; i < s1; i += 256) m = fmaxf(m, gate[i]);
    red[tid] = m;
    __syncthreads();
    for (int off = 128; off; off >>= 1) {
        if (tid < off) red[tid] = fmaxf(red[tid], red[tid + off]);
        __syncthreads();
    }
    float gm = red[0];
    __syncthreads();
    float s = 0.f;
    for (int i = s0 + tid; i < s1; i += 256) s += __expf(gate[i] - gm);
    red[tid] = s;
    __syncthreads();
    for (int off = 128; off; off >>= 1) {
        if (tid < off) red[tid] += red[tid + off];
        __syncthreads();
    }
    if (tid == 0) {
        gmax[b] = gm;
        gden[b] = red[0];
    }
}

// K7c: per-node pooling weight
__global__ void wgt_kernel(const float* __restrict__ gate, const int* __restrict__ batch,
                           const float* __restrict__ gmax, const float* __restrict__ gden,
                           float* __restrict__ wgt, int N) {
    int n = blockIdx.x * 256 + threadIdx.x;
    if (n >= N) return;
    int b = batch[n];
    wgt[n] = __expf(gate[n] - gmax[b]) / gden[b];
}

// K7d: scatter-accumulate pooled embedding.
#define POOL_CHUNK 32
__global__ __launch_bounds__(256) void pool_scatter_kernel(
    const float* __restrict__ h, const float* __restrict__ wgt,
    const int* __restrict__ batch, float* __restrict__ g_embed, int N) {
    int i0 = blockIdx.x * POOL_CHUNK;
    int d = threadIdx.x;
    int iend = min(i0 + POOL_CHUNK, N);
    float acc = 0.f;
    int cur = batch[i0];
    for (int i = i0; i < iend; ++i) {
        int b = batch[i];
        if (b != cur) {
            atomicAdd(&g_embed[cur * DD + d], acc);
            acc = 0.f;
            cur = b;
        }
        acc += wgt[i] * h[(size_t)i * DD + d];
    }
    atomicAdd(&g_embed[cur * DD + d], acc);
}

// K8: readout MLP [B,256] -> [B,256]
__global__ __launch_bounds__(256) void readout_kernel(
    const float* __restrict__ g_embed, const float* __restrict__ w1,
    const float* __restrict__ b1, const float* __restrict__ w2,
    const float* __restrict__ b2, float* __restrict__ out) {
    int b = blockIdx.x;
    int tid = threadIdx.x;
    __shared__ float gvec[256];
    __shared__ float hid[256];
    gvec[tid] = g_embed[b * DD + tid];
    __syncthreads();
    float hv = b1[tid];
    for (int k = 0; k < DD; ++k) hv += gvec[k] * w1[k * DD + tid];
    hid[tid] = fmaxf(hv, 0.f);
    __syncthreads();
    float o = b2[tid];
    for (int t = 0; t < DD; ++t) o += hid[t] * w2[t * DD + tid];
    out[b * DD + tid] = o;
}

// ---------------------------------------------------------------------------
extern "C" void kernel_launch(void* const* d_in, const int* in_sizes, int n_in,
                              void* d_out, int out_size, void* d_ws, size_t ws_size,
                              hipStream_t stream) {
    const float* x        = (const float*)d_in[0];
    const float* edge_attr= (const float*)d_in[1];
    const int*   edge_idx = (const int*)d_in[2];
    const int*   batch    = (const int*)d_in[3];
    const float* enc_w    = (const float*)d_in[4];
    const float* enc_b    = (const float*)d_in[5];
    const float* eenc_w   = (const float*)d_in[6];
    const float* eenc_b   = (const float*)d_in[7];
    const float* gat_w    = (const float*)d_in[8];
    const float* att_src  = (const float*)d_in[9];
    const float* att_dst  = (const float*)d_in[10];
    const float* att_edge = (const float*)d_in[11];
    const float* gat_ew   = (const float*)d_in[12];
    const float* gat_b    = (const float*)d_in[13];
    const float* ln_g     = (const float*)d_in[14];
    const float* ln_b     = (const float*)d_in[15];
    const float* gate_w1  = (const float*)d_in[16];
    const float* gate_b1  = (const float*)d_in[17];
    const float* gate_w2  = (const float*)d_in[18];
    const float* gate_b2  = (const float*)d_in[19];
    const float* ro_w1    = (const float*)d_in[20];
    const float* ro_b1    = (const float*)d_in[21];
    const float* ro_w2    = (const float*)d_in[22];
    const float* ro_b2    = (const float*)d_in[23];
    float* out = (float*)d_out;

    const int N = in_sizes[0] / 42;       // 10000
    const int E = in_sizes[1] / 12;       // 160000
    const int B = out_size / DD;          // 16

    // workspace carve-up
    char* p = (char*)d_ws;
    auto alloc = [&](size_t bytes) {
        char* r = p;
        p += (bytes + 255) & ~(size_t)255;
        return (void*)r;
    };
    float* h        = (float*)alloc((size_t)N * DD * 4);
    float* xh       = (float*)alloc((size_t)N * DD * 4);
    float* a_s      = (float*)alloc((size_t)N * HH * 4);
    float* a_d      = (float*)alloc((size_t)N * HH * 4);
    float* a_e_all  = (float*)alloc((size_t)(E + N) * LH * 4);  // [e][l*4+h]
    float* wproj    = (float*)alloc((size_t)DD * LH * 4);
    float* wpack    = (float*)alloc((size_t)DD * 36 * 4);
    float* gate     = (float*)alloc((size_t)N * 4);
    float* g_embed  = (float*)alloc((size_t)B * DD * 4);
    float* gmax     = (float*)alloc((size_t)B * 4);
    float* gden     = (float*)alloc((size_t)B * 4);
    float* wgt      = (float*)alloc((size_t)N * 4);
    int* deg        = (int*)alloc((size_t)N * 4);
    int* row_ptr    = (int*)alloc((size_t)(N + 1) * 4);
    int* cursor     = (int*)alloc((size_t)N * 4);
    int* csr_src    = (int*)alloc((size_t)E * 4);
    int* csr_eid    = (int*)alloc((size_t)E * 4);
    int* bstart     = (int*)alloc((size_t)(B + 1) * 4);

    const int* src_arr = edge_idx;
    const int* dst_arr = edge_idx + E;

    hipMemsetAsync(deg, 0, (size_t)N * 4, stream);
    hipMemsetAsync(g_embed, 0, (size_t)B * DD * 4, stream);

    wproj_kernel<<<LL, 256, 0, stream>>>(gat_ew, att_edge, wproj);
    wpack_kernel<<<1, 256, 0, stream>>>(eenc_w, eenc_b, wproj, wpack);
    encoder_kernel<<<N, 256, 0, stream>>>(x, enc_w, enc_b, h, N);
    deg_kernel<<<(E + 255) / 256, 256, 0, stream>>>(dst_arr, deg, E);
    scan_kernel<<<1, 1024, 0, stream>>>(deg, row_ptr, N);
    copy_int_kernel<<<(N + 255) / 256, 256, 0, stream>>>(row_ptr, cursor, N);
    scatter_kernel<<<(E + 255) / 256, 256, 0, stream>>>(
        src_arr, dst_arr, cursor, csr_src, csr_eid, E);
    edge_pre_kernel<<<(E + 255) / 256, 256, 0, stream>>>(
        edge_attr, wpack, a_e_all, E);
    self_ae_kernel<<<(N * LH + 255) / 256, 256, 0, stream>>>(
        row_ptr, csr_eid, a_e_all, N, E);

    dim3 ggrid((N + 63) / 64, 4);
    for (int l = 0; l < LL; ++l) {
        gemm256_kernel<<<ggrid, 256, 0, stream>>>(
            h, gat_w + (size_t)l * DD * DD, nullptr, xh, N, 0,
            att_src + l * DD, att_dst + l * DD, a_s, a_d);
        gat_message3_kernel<<<N, 256, 0, stream>>>(
            xh, a_s, a_d, a_e_all + l * HH, row_ptr, csr_src, csr_eid,
            gat_b + l * DD, ln_g + l * DD, ln_b + l * DD, h, N, E);
    }

    // pooling gate MLP: hidden = relu(h @ gate_w1 + gate_b1) into xh (reuse)
    gemm256_kernel<<<ggrid, 256, 0, stream>>>(h, gate_w1, gate_b1, xh, N, 1,
                                              nullptr, nullptr, nullptr, nullptr);
    gate_kernel<<<N, 256, 0, stream>>>(xh, gate_w2, gate_b2, gate, N);
    bstart_kernel<<<1, 32, 0, stream>>>(batch, bstart, N, B);
    gseg_kernel<<<B, 256, 0, stream>>>(gate, bstart, gmax, gden);
    wgt_kernel<<<(N + 255) / 256, 256, 0, stream>>>(gate, batch, gmax, gden, wgt, N);
    pool_scatter_kernel<<<(N + POOL_CHUNK - 1) / POOL_CHUNK, 256, 0, stream>>>(
        h, wgt, batch, g_embed, N);
    readout_kernel<<<B, 256, 0, stream>>>(g_embed, ro_w1, ro_b1, ro_w2, ro_b2, out);
}